// Round 3
// baseline (240.509 us; speedup 1.0000x reference)
//
#include <hip/hip_runtime.h>
#include <hip/hip_fp16.h>

// TriMipEncoding: N pts, 3 planes (512^2, 16 ch), 8 mip levels, trilinear sample.
//
// Fast path (ws_size >= 33.6 MB): full fp16 pyramid (levels 0..7) in d_ws.
//   Texel = 16 halfs = 32 B. Per-plane texel offset of level l:
//   off(l) = (2^20 - (2^20 >> 2l)) / 3. Plane stride = 349520 texels.
// R3: sampler duration identical at FETCH=0 vs FETCH=122MB -> NOT HBM-bound.
// R4: stage levels 5..7 (31.5 KB, all planes) in LDS. Block=512, 4 blk/CU.
// R5 FAILED (1 thread/pt): per-lane 192B stores amplify writes (106->195MB),
//   occupancy 33%. Lesson: wave-contiguous stores are load-bearing.
// R6 NEUTRAL (LDS-stage xyz/level): removing 24 broadcast lane-addrs/pt
//   changed nothing -> cost is per-INSTRUCTION + per-LINE, not per-lane.
// R7 (this round): the l>=5 LDS/global branch diverges in ~every wave
//   (l0 uniform{0..6} over ~10.7 pts/wave) -> both paths execute: 16
//   half-masked tap instrs/wave. Counting-sort points by l0 (order[] in
//   ws after pyramid) -> level-uniform waves: 8 fully-active tap instrs,
//   ~29% of points pure-LDS, per-level L2 locality. Stores keep the
//   6-lane/point layout (192 B region covered by 2 back-to-back st4s).

typedef float        f4v   __attribute__((ext_vector_type(4)));
typedef unsigned int u32x2 __attribute__((ext_vector_type(2)));
typedef unsigned int u32x4 __attribute__((ext_vector_type(4)));

#define FM_PLANE_STRIDE (262144 * 16)   // floats per plane in fm
#define WS_PLANE_STRIDE (87376 * 16)    // floats per plane, fp32 fallback pyramid
#define PSTRIDE_H (349520 * 16)         // halfs per plane, fp16 full pyramid
#define WS_H_BYTES (3ull * PSTRIDE_H * 2ull)
#define LVL5_OFF 349184u                // texel offset of level 5 (levels 5..7 contiguous)

__device__ __forceinline__ unsigned lvl_off(int l) {   // texel offset of level l
    return (1048576u - (1048576u >> (2 * l))) / 3u;
}

__device__ __forceinline__ f4v ld4(const float* p) {
    return *reinterpret_cast<const f4v*>(p);
}
__device__ __forceinline__ f4v ld4nt(const float* p) {
    return __builtin_nontemporal_load(reinterpret_cast<const f4v*>(p));
}
__device__ __forceinline__ void st4(float* p, f4v v) {
    *reinterpret_cast<f4v*>(p) = v;
}
__device__ __forceinline__ void st4nt(float* p, f4v v) {
    __builtin_nontemporal_store(v, reinterpret_cast<f4v*>(p));
}
__device__ __forceinline__ f4v ldraw_h(const __half* p) {   // 8 halfs as raw f4v
    return *reinterpret_cast<const f4v*>(p);
}
__device__ __forceinline__ u32x2 pack4(f4v v) {             // 4 floats -> 4 halfs
    __half2 lo = __floats2half2_rn(v.x, v.y);
    __half2 hi = __floats2half2_rn(v.z, v.w);
    u32x2 r;
    r.x = *reinterpret_cast<unsigned*>(&lo);
    r.y = *reinterpret_cast<unsigned*>(&hi);
    return r;
}
__device__ __forceinline__ f4v h4f(const __half* p) {       // 4 halfs -> 4 floats
    u32x2 u = *reinterpret_cast<const u32x2*>(p);
    unsigned a0 = u.x, a1 = u.y;
    __half2 lo = *reinterpret_cast<__half2*>(&a0);
    __half2 hi = *reinterpret_cast<__half2*>(&a1);
    float2 flo = __half22float2(lo), fhi = __half22float2(hi);
    f4v r; r.x = flo.x; r.y = flo.y; r.z = fhi.x; r.w = fhi.y;
    return r;
}
__device__ __forceinline__ float2 up2(float rawcomp) {      // 2 packed halfs -> 2 floats
    unsigned u = __float_as_uint(rawcomp);
    __half2 hh = *reinterpret_cast<__half2*>(&u);
    return __half22float2(hh);
}

// ---------------- fp16 path ----------------

// fm (fp32) -> L0' (fp16) + L1 (fp16). Thread per (L1 texel, quad q); grid (1024, 3).
__global__ __launch_bounds__(256) void mip_convert_l1(
    const float* __restrict__ fm, __half* __restrict__ wsh)
{
    int t = blockIdx.x * 256 + threadIdx.x;
    const int p = blockIdx.y;
    const int q = t & 3, idx = t >> 2;
    const int y = idx >> 8, x = idx & 255;
    const float* sp = fm + (size_t)p * FM_PLANE_STRIDE
                         + ((size_t)(2 * y) * 512 + 2 * x) * 16 + q * 4;
    f4v a = ld4nt(sp);
    f4v b = ld4nt(sp + 16);
    f4v c = ld4nt(sp + 512 * 16);
    f4v d = ld4nt(sp + 512 * 16 + 16);
    __half* L0 = wsh + (size_t)p * PSTRIDE_H;
    size_t o00 = ((size_t)(2 * y) * 512 + 2 * x) * 16 + q * 4;
    *reinterpret_cast<u32x2*>(L0 + o00)                 = pack4(a);
    *reinterpret_cast<u32x2*>(L0 + o00 + 16)            = pack4(b);
    *reinterpret_cast<u32x2*>(L0 + o00 + 512 * 16)      = pack4(c);
    *reinterpret_cast<u32x2*>(L0 + o00 + 512 * 16 + 16) = pack4(d);
    f4v m = (a + b + c + d) * 0.25f;   // L1 from fp32 source, single rounding
    __half* L1 = wsh + (size_t)p * PSTRIDE_H + (size_t)262144 * 16;
    *reinterpret_cast<u32x2*>(L1 + ((size_t)y * 256 + x) * 16 + q * 4) = pack4(m);
}

// Fused L2..L7 (fp16). Block = (32x32 L2 tile, quad q, plane p); grid (16,4,3).
__global__ __launch_bounds__(256) void mip_tail_h(__half* __restrict__ wsh)
{
    const int tile = blockIdx.x;
    const int q    = blockIdx.y;
    const int p    = blockIdx.z;
    const int ty = tile >> 2, tx = tile & 3;
    const int tid = threadIdx.x;

    __shared__ f4v A[32 * 32];
    __shared__ f4v B[16 * 16];

    __half* plane = wsh + (size_t)p * PSTRIDE_H;
    const __half* L1 = plane + (size_t)lvl_off(1) * 16;
    __half* L2 = plane + (size_t)lvl_off(2) * 16;
    __half* L3 = plane + (size_t)lvl_off(3) * 16;
    __half* L4 = plane + (size_t)lvl_off(4) * 16;
    __half* L5 = plane + (size_t)lvl_off(5) * 16;
    __half* L6 = plane + (size_t)lvl_off(6) * 16;
    __half* L7 = plane + (size_t)lvl_off(7) * 16;

    #pragma unroll
    for (int k = 0; k < 4; ++k) {
        int li = tid + k * 256;
        int ly = li >> 5, lx = li & 31;
        int gy = ty * 32 + ly, gx = tx * 32 + lx;
        const __half* sp = L1 + ((size_t)(2 * gy) * 256 + 2 * gx) * 16 + q * 4;
        f4v r = (h4f(sp) + h4f(sp + 16) + h4f(sp + 256 * 16) + h4f(sp + 256 * 16 + 16)) * 0.25f;
        A[li] = r;
        *reinterpret_cast<u32x2*>(L2 + ((size_t)gy * 128 + gx) * 16 + q * 4) = pack4(r);
    }
    __syncthreads();

    {   // L3: 16x16
        int ly = tid >> 4, lx = tid & 15;
        f4v r = (A[(2 * ly) * 32 + 2 * lx]     + A[(2 * ly) * 32 + 2 * lx + 1] +
                 A[(2 * ly + 1) * 32 + 2 * lx] + A[(2 * ly + 1) * 32 + 2 * lx + 1]) * 0.25f;
        B[tid] = r;
        *reinterpret_cast<u32x2*>(L3 + ((size_t)(ty * 16 + ly) * 64 + tx * 16 + lx) * 16 + q * 4) = pack4(r);
    }
    __syncthreads();

    if (tid < 64) {   // L4: 8x8
        int ly = tid >> 3, lx = tid & 7;
        f4v r = (B[(2 * ly) * 16 + 2 * lx]     + B[(2 * ly) * 16 + 2 * lx + 1] +
                 B[(2 * ly + 1) * 16 + 2 * lx] + B[(2 * ly + 1) * 16 + 2 * lx + 1]) * 0.25f;
        A[tid] = r;
        *reinterpret_cast<u32x2*>(L4 + ((size_t)(ty * 8 + ly) * 32 + tx * 8 + lx) * 16 + q * 4) = pack4(r);
    }
    __syncthreads();

    if (tid < 16) {   // L5: 4x4
        int ly = tid >> 2, lx = tid & 3;
        f4v r = (A[(2 * ly) * 8 + 2 * lx]     + A[(2 * ly) * 8 + 2 * lx + 1] +
                 A[(2 * ly + 1) * 8 + 2 * lx] + A[(2 * ly + 1) * 8 + 2 * lx + 1]) * 0.25f;
        B[tid] = r;
        *reinterpret_cast<u32x2*>(L5 + ((size_t)(ty * 4 + ly) * 16 + tx * 4 + lx) * 16 + q * 4) = pack4(r);
    }
    __syncthreads();

    if (tid < 4) {    // L6: 2x2
        int ly = tid >> 1, lx = tid & 1;
        f4v r = (B[(2 * ly) * 4 + 2 * lx]     + B[(2 * ly) * 4 + 2 * lx + 1] +
                 B[(2 * ly + 1) * 4 + 2 * lx] + B[(2 * ly + 1) * 4 + 2 * lx + 1]) * 0.25f;
        A[tid] = r;
        *reinterpret_cast<u32x2*>(L6 + ((size_t)(ty * 2 + ly) * 8 + tx * 2 + lx) * 16 + q * 4) = pack4(r);
    }
    __syncthreads();

    if (tid == 0) {   // L7: 1 texel
        f4v r = (A[0] + A[1] + A[2] + A[3]) * 0.25f;
        *reinterpret_cast<u32x2*>(L7 + ((size_t)ty * 4 + tx) * 16 + q * 4) = pack4(r);
    }
}

// ---------------- level counting sort (8 buckets) ----------------
// meta layout (u32): [0..8) cnt, [8..16) base, [16..24) cursor.

__global__ void lvl_zero(unsigned* __restrict__ meta)
{
    if (threadIdx.x < 24) meta[threadIdx.x] = 0;
}

__device__ __forceinline__ int lvl_bucket(float lv)
{
    lv = fminf(fmaxf(lv, 0.f), 7.f);
    return (int)floorf(lv);          // 0..7 (7 only when lv == 7.0)
}

__global__ __launch_bounds__(512) void lvl_hist(
    const float* __restrict__ level, unsigned* __restrict__ meta, int N)
{
    __shared__ unsigned lh[8];
    if (threadIdx.x < 8) lh[threadIdx.x] = 0;
    __syncthreads();
    int n = blockIdx.x * 512 + threadIdx.x;
    if (n < N) atomicAdd(&lh[lvl_bucket(level[n])], 1u);
    __syncthreads();
    if (threadIdx.x < 8 && lh[threadIdx.x])
        atomicAdd(&meta[threadIdx.x], lh[threadIdx.x]);
}

__global__ void lvl_scan(unsigned* __restrict__ meta)
{
    if (threadIdx.x == 0) {
        unsigned s = 0;
        #pragma unroll
        for (int i = 0; i < 8; ++i) {
            meta[8 + i] = s;          // base
            s += meta[i];
            meta[16 + i] = 0;         // cursor
        }
    }
}

__global__ __launch_bounds__(512) void lvl_scatter(
    const float* __restrict__ level, unsigned* __restrict__ meta,
    unsigned* __restrict__ order, int N)
{
    __shared__ unsigned lh[8];
    __shared__ unsigned lbase[8];
    if (threadIdx.x < 8) lh[threadIdx.x] = 0;
    __syncthreads();
    int n = blockIdx.x * 512 + threadIdx.x;
    int b = 0; unsigned rank = 0;
    if (n < N) {
        b = lvl_bucket(level[n]);
        rank = atomicAdd(&lh[b], 1u);
    }
    __syncthreads();
    if (threadIdx.x < 8) {
        unsigned c = lh[threadIdx.x];
        lbase[threadIdx.x] = c ? atomicAdd(&meta[16 + threadIdx.x], c) : 0u;
    }
    __syncthreads();
    if (n < N) order[meta[8 + b] + lbase[b] + rank] = (unsigned)n;
}

// ---------------- sampler ----------------

// Weighted 8-channel bilinear tap; levels >= 5 read from LDS copy.
__device__ __forceinline__ void bilerp8(
    const __half* __restrict__ wsh, const __half* __restrict__ lds_h,
    int p, int l, float u, float v, int h, float* o)
{
    const int sz = 512 >> l;
    const float fsz = (float)sz;
    float px = u * fsz - 0.5f;
    float py = v * fsz - 0.5f;
    float xf = floorf(px), yf = floorf(py);
    float fx = px - xf, fy = py - yf;
    int xi = (int)xf, yi = (int)yf;
    int xa = min(max(xi, 0), sz - 1);
    int xb = min(xi + 1, sz - 1);      // xi >= -1 always
    int ya = min(max(yi, 0), sz - 1);
    int yb = min(yi + 1, sz - 1);
    f4v q00, q01, q10, q11;
    if (l >= 5) {
        const int sel = (l == 6) ? 256 : ((l == 7) ? 320 : 0);
        const __half* base = lds_h + (size_t)(p * 336 + sel) * 16 + h * 8;
        const __half* r0 = base + (ya * sz) * 16;
        const __half* r1 = base + (yb * sz) * 16;
        q00 = ldraw_h(r0 + xa * 16);
        q01 = ldraw_h(r0 + xb * 16);
        q10 = ldraw_h(r1 + xa * 16);
        q11 = ldraw_h(r1 + xb * 16);
    } else {
        const __half* base = wsh + (size_t)p * PSTRIDE_H + (size_t)lvl_off(l) * 16 + h * 8;
        const __half* r0 = base + (size_t)(ya * sz) * 16;
        const __half* r1 = base + (size_t)(yb * sz) * 16;
        q00 = ldraw_h(r0 + (size_t)xa * 16);
        q01 = ldraw_h(r0 + (size_t)xb * 16);
        q10 = ldraw_h(r1 + (size_t)xa * 16);
        q11 = ldraw_h(r1 + (size_t)xb * 16);
    }
    float gx = 1.f - fx, gy = 1.f - fy;
    float w00 = gx * gy, w01 = fx * gy, w10 = gx * fy, w11 = fx * fy;
    #pragma unroll
    for (int i = 0; i < 4; ++i) {
        float2 a = up2(q00[i]), b = up2(q01[i]), c = up2(q10[i]), d = up2(q11[i]);
        o[2 * i]     = a.x * w00 + b.x * w01 + c.x * w10 + d.x * w11;
        o[2 * i + 1] = a.y * w00 + b.y * w01 + c.y * w10 + d.y * w11;
    }
}

// One thread per (sorted point sp, plane p, half h): w = (sp*3 + p)*2 + h.
// order != nullptr: sp -> n via level-sorted permutation (wave-uniform l0).
// Block 512; LDS holds levels 5..7 of all 3 planes (31.5 KB).
__global__ __launch_bounds__(512) void trimip_sample_h(
    const float* __restrict__ xyz, const float* __restrict__ level,
    const __half* __restrict__ wsh, const unsigned* __restrict__ order,
    float* __restrict__ out, int N)
{
    __shared__ u32x4 lds[2016];       // 3 planes * 336 texels * 32 B = 32256 B
    for (int uidx = threadIdx.x; uidx < 2016; uidx += 512) {
        int p = uidx / 672;           // 672 16-B units per plane
        int rem = uidx - p * 672;
        lds[uidx] = *reinterpret_cast<const u32x4*>(
            wsh + (size_t)p * PSTRIDE_H + (size_t)LVL5_OFF * 16 + (size_t)rem * 8);
    }
    __syncthreads();
    const __half* lds_h = reinterpret_cast<const __half*>(lds);

    int w = blockIdx.x * 512 + threadIdx.x;
    if (w >= N * 6) return;
    const int h = w & 1;
    const int r = w >> 1;
    const int sp = r / 3;
    const int p = r - sp * 3;
    const int n = order ? (int)order[sp] : sp;

    const float c0 = xyz[n * 3 + 0];
    const float c1 = xyz[n * 3 + 1];
    const float c2 = xyz[n * 3 + 2];
    const float u = (p == 0) ? c1 : c0;
    const float v = (p == 2) ? c1 : c2;

    float lv = level[n];
    lv = fminf(fmaxf(lv, 0.f), 7.f);
    float lf = floorf(lv);
    float f = lv - lf;
    int l0 = (int)lf;
    int l1 = min(l0 + 1, 7);

    float s0[8], s1[8];
    bilerp8(wsh, lds_h, p, l0, u, v, h, s0);
    bilerp8(wsh, lds_h, p, l1, u, v, h, s1);
    float g = 1.f - f;
    f4v oa, ob;
    #pragma unroll
    for (int i = 0; i < 4; ++i) {
        oa[i] = s0[i] * g + s1[i] * f;
        ob[i] = s0[4 + i] * g + s1[4 + i] * f;
    }
    float* op = out + (size_t)((n * 3 + p) * 2 + h) * 8;
    st4nt(op, oa);
    st4nt(op + 4, ob);
}

// ---------------- fp32 fallback path ----------------

__device__ __forceinline__ f4v avg4(f4v a, f4v b, f4v c, f4v d) {
    return (a + b + c + d) * 0.25f;
}

__global__ __launch_bounds__(256) void mip_build_f(
    const float* __restrict__ src, float* __restrict__ dst)
{
    int t = blockIdx.x * blockDim.x + threadIdx.x;
    const int p = blockIdx.y;
    const int q = t & 3, idx = t >> 2;
    const int y = idx >> 8, x = idx & 255;
    const float* sp = src + (size_t)p * FM_PLANE_STRIDE
                          + ((size_t)(2 * y) * 512 + 2 * x) * 16 + q * 4;
    f4v r = avg4(ld4(sp), ld4(sp + 16), ld4(sp + 512 * 16), ld4(sp + 512 * 16 + 16));
    st4(dst + (size_t)p * WS_PLANE_STRIDE + ((size_t)y * 256 + x) * 16 + q * 4, r);
}

__global__ __launch_bounds__(256) void mip_tail_f(float* __restrict__ mips)
{
    const int tile = blockIdx.x, q = blockIdx.y, p = blockIdx.z;
    const int ty = tile >> 2, tx = tile & 3;
    const int tid = threadIdx.x;
    __shared__ f4v A[32 * 32];
    __shared__ f4v B[16 * 16];
    float* plane = mips + (size_t)p * WS_PLANE_STRIDE;
    const float* L1 = plane;
    float* L2 = plane + (size_t)65536 * 16;
    float* L3 = plane + (size_t)81920 * 16;
    float* L4 = plane + (size_t)86016 * 16;
    float* L5 = plane + (size_t)87040 * 16;
    float* L6 = plane + (size_t)87296 * 16;
    float* L7 = plane + (size_t)87360 * 16;

    #pragma unroll
    for (int k = 0; k < 4; ++k) {
        int li = tid + k * 256;
        int ly = li >> 5, lx = li & 31;
        int gy = ty * 32 + ly, gx = tx * 32 + lx;
        const float* sp = L1 + ((size_t)(2 * gy) * 256 + 2 * gx) * 16 + q * 4;
        f4v r = avg4(ld4(sp), ld4(sp + 16), ld4(sp + 256 * 16), ld4(sp + 256 * 16 + 16));
        A[li] = r;
        st4(L2 + ((size_t)gy * 128 + gx) * 16 + q * 4, r);
    }
    __syncthreads();
    {
        int ly = tid >> 4, lx = tid & 15;
        f4v r = avg4(A[(2 * ly) * 32 + 2 * lx],     A[(2 * ly) * 32 + 2 * lx + 1],
                     A[(2 * ly + 1) * 32 + 2 * lx], A[(2 * ly + 1) * 32 + 2 * lx + 1]);
        B[tid] = r;
        st4(L3 + ((size_t)(ty * 16 + ly) * 64 + tx * 16 + lx) * 16 + q * 4, r);
    }
    __syncthreads();
    if (tid < 64) {
        int ly = tid >> 3, lx = tid & 7;
        f4v r = avg4(B[(2 * ly) * 16 + 2 * lx],     B[(2 * ly) * 16 + 2 * lx + 1],
                     B[(2 * ly + 1) * 16 + 2 * lx], B[(2 * ly + 1) * 16 + 2 * lx + 1]);
        A[tid] = r;
        st4(L4 + ((size_t)(ty * 8 + ly) * 32 + tx * 8 + lx) * 16 + q * 4, r);
    }
    __syncthreads();
    if (tid < 16) {
        int ly = tid >> 2, lx = tid & 3;
        f4v r = avg4(A[(2 * ly) * 8 + 2 * lx],     A[(2 * ly) * 8 + 2 * lx + 1],
                     A[(2 * ly + 1) * 8 + 2 * lx], A[(2 * ly + 1) * 8 + 2 * lx + 1]);
        B[tid] = r;
        st4(L5 + ((size_t)(ty * 4 + ly) * 16 + tx * 4 + lx) * 16 + q * 4, r);
    }
    __syncthreads();
    if (tid < 4) {
        int ly = tid >> 1, lx = tid & 1;
        f4v r = avg4(B[(2 * ly) * 4 + 2 * lx],     B[(2 * ly) * 4 + 2 * lx + 1],
                     B[(2 * ly + 1) * 4 + 2 * lx], B[(2 * ly + 1) * 4 + 2 * lx + 1]);
        A[tid] = r;
        st4(L6 + ((size_t)(ty * 2 + ly) * 8 + tx * 2 + lx) * 16 + q * 4, r);
    }
    __syncthreads();
    if (tid == 0) {
        f4v r = avg4(A[0], A[1], A[2], A[3]);
        st4(L7 + ((size_t)ty * 4 + tx) * 16 + q * 4, r);
    }
}

__device__ __forceinline__ f4v bilerp_f(
    const float* __restrict__ fm, const float* __restrict__ mips,
    int p, int l, float u, float v, int q)
{
    const int sz = 512 >> l;
    const float fsz = (float)sz;
    float px = u * fsz - 0.5f;
    float py = v * fsz - 0.5f;
    float xf = floorf(px), yf = floorf(py);
    float fx = px - xf, fy = py - yf;
    int xi = (int)xf, yi = (int)yf;
    int xa = min(max(xi, 0), sz - 1);
    int xb = min(xi + 1, sz - 1);
    int ya = min(max(yi, 0), sz - 1);
    int yb = min(yi + 1, sz - 1);
    const float* base;
    if (l == 0) {
        base = fm + (size_t)p * FM_PLANE_STRIDE;
    } else {
        unsigned off = (262144u - ((unsigned)(sz * sz) << 2)) / 3u;
        base = mips + (size_t)p * WS_PLANE_STRIDE + (size_t)off * 16;
    }
    const float* r0 = base + (size_t)(ya * sz) * 16 + q * 4;
    const float* r1 = base + (size_t)(yb * sz) * 16 + q * 4;
    f4v f00 = ld4(r0 + xa * 16);
    f4v f01 = ld4(r0 + xb * 16);
    f4v f10 = ld4(r1 + xa * 16);
    f4v f11 = ld4(r1 + xb * 16);
    float gx = 1.f - fx, gy = 1.f - fy;
    return (f00 * gx + f01 * fx) * gy + (f10 * gx + f11 * fx) * fy;
}

__global__ __launch_bounds__(256) void trimip_sample_f(
    const float* __restrict__ xyz, const float* __restrict__ level,
    const float* __restrict__ fm, const float* __restrict__ mips,
    float* __restrict__ out, int N)
{
    int t = blockIdx.x * blockDim.x + threadIdx.x;
    if (t >= N * 12) return;
    const int q = t & 3;
    const int r = t >> 2;
    const int n = r / 3;
    const int p = r - n * 3;
    const float c0 = xyz[n * 3 + 0];
    const float c1 = xyz[n * 3 + 1];
    const float c2 = xyz[n * 3 + 2];
    const float u = (p == 0) ? c1 : c0;
    const float v = (p == 2) ? c1 : c2;
    float lv = level[n];
    lv = fminf(fmaxf(lv, 0.f), 7.f);
    float lf = floorf(lv);
    float f = lv - lf;
    int l0 = (int)lf;
    int l1 = min(l0 + 1, 7);
    f4v s0 = bilerp_f(fm, mips, p, l0, u, v, q);
    f4v s1 = bilerp_f(fm, mips, p, l1, u, v, q);
    f4v o = s0 * (1.f - f) + s1 * f;
    st4nt(out + (size_t)t * 4, o);
}

extern "C" void kernel_launch(void* const* d_in, const int* in_sizes, int n_in,
                              void* d_out, int out_size, void* d_ws, size_t ws_size,
                              hipStream_t stream) {
    const float* xyz   = (const float*)d_in[0];
    const float* level = (const float*)d_in[1];
    const float* fm    = (const float*)d_in[2];
    float* out = (float*)d_out;
    const int N = in_sizes[1];

    if (ws_size >= WS_H_BYTES) {
        __half* wsh = (__half*)d_ws;
        mip_convert_l1<<<dim3(1024, 3), dim3(256), 0, stream>>>(fm, wsh);
        mip_tail_h<<<dim3(16, 4, 3), dim3(256), 0, stream>>>(wsh);

        const size_t sort_bytes = WS_H_BYTES + (size_t)N * 4 + 96;
        unsigned* order = nullptr;
        if (ws_size >= sort_bytes) {
            order = (unsigned*)((char*)d_ws + WS_H_BYTES);
            unsigned* meta = order + N;                       // 24 u32
            const int blocks = (N + 511) / 512;
            lvl_zero<<<1, 32, 0, stream>>>(meta);
            lvl_hist<<<blocks, 512, 0, stream>>>(level, meta, N);
            lvl_scan<<<1, 32, 0, stream>>>(meta);
            lvl_scatter<<<blocks, 512, 0, stream>>>(level, meta, order, N);
        }
        const int total = N * 6;
        trimip_sample_h<<<(total + 511) / 512, 512, 0, stream>>>(
            xyz, level, wsh, order, out, N);
    } else {
        float* mips = (float*)d_ws;
        mip_build_f<<<dim3(1024, 3), dim3(256), 0, stream>>>(fm, mips);
        mip_tail_f<<<dim3(16, 4, 3), dim3(256), 0, stream>>>(mips);
        const int total = N * 12;
        trimip_sample_f<<<(total + 255) / 256, 256, 0, stream>>>(xyz, level, fm, mips, out, N);
    }
}

// Round 4
// 200.755 us; speedup vs baseline: 1.1980x; 1.1980x over previous
//
#include <hip/hip_runtime.h>
#include <hip/hip_fp16.h>

// TriMipEncoding: N pts, 3 planes (512^2, 16 ch), 8 mip levels, trilinear sample.
//
// Fast path (ws_size >= 33.6 MB): full fp16 pyramid (levels 0..7) in d_ws.
//   Texel = 16 halfs = 32 B. Per-plane texel offset of level l:
//   off(l) = (2^20 - (2^20 >> 2l)) / 3. Plane stride = 349520 texels.
// R3: sampler duration identical at FETCH=0 vs FETCH=122MB -> NOT HBM-bound.
// R4: stage levels 5..7 (31.5 KB, all planes) in LDS. Block=512, 4 blk/CU.
// R5 FAILED (1 thread/pt): per-lane 192B stores amplify writes, occupancy
//   33% -> 2.3x slower at ~same line count. KEY: time scales with
//   CONCURRENCY -> latency-bound.
// R6 NEUTRAL: removing 24 broadcast lane-addrs/pt changed nothing.
// R7 NEUTRAL: level-sorted waves (uniform l0, tap instrs halved) changed
//   nothing; sort kernels cost 37 us. Falsifies divergence/instruction
//   models. Surviving model: gather-LATENCY-bound (taps are L2 misses,
//   FETCH=120MB/dispatch), concurrency-limited.
// R8 (this round): drop the sort; raise per-thread MLP: issue all 8 tap
//   loads (l0+l1) in one clause, THEN combine (compiler emits counted
//   vmcnt(4)/vmcnt(0)) -> one exposed latency window per thread instead
//   of two. __launch_bounds__(512,8) pins 4 blocks/CU (VGPR cap) so the
//   fatter live range cannot halve occupancy.

typedef float        f4v   __attribute__((ext_vector_type(4)));
typedef unsigned int u32x2 __attribute__((ext_vector_type(2)));
typedef unsigned int u32x4 __attribute__((ext_vector_type(4)));

#define FM_PLANE_STRIDE (262144 * 16)   // floats per plane in fm
#define WS_PLANE_STRIDE (87376 * 16)    // floats per plane, fp32 fallback pyramid
#define PSTRIDE_H (349520 * 16)         // halfs per plane, fp16 full pyramid
#define WS_H_BYTES (3ull * PSTRIDE_H * 2ull)
#define LVL5_OFF 349184u                // texel offset of level 5 (levels 5..7 contiguous)

__device__ __forceinline__ unsigned lvl_off(int l) {   // texel offset of level l
    return (1048576u - (1048576u >> (2 * l))) / 3u;
}

__device__ __forceinline__ f4v ld4(const float* p) {
    return *reinterpret_cast<const f4v*>(p);
}
__device__ __forceinline__ f4v ld4nt(const float* p) {
    return __builtin_nontemporal_load(reinterpret_cast<const f4v*>(p));
}
__device__ __forceinline__ void st4(float* p, f4v v) {
    *reinterpret_cast<f4v*>(p) = v;
}
__device__ __forceinline__ void st4nt(float* p, f4v v) {
    __builtin_nontemporal_store(v, reinterpret_cast<f4v*>(p));
}
__device__ __forceinline__ f4v ldraw_h(const __half* p) {   // 8 halfs as raw f4v
    return *reinterpret_cast<const f4v*>(p);
}
__device__ __forceinline__ u32x2 pack4(f4v v) {             // 4 floats -> 4 halfs
    __half2 lo = __floats2half2_rn(v.x, v.y);
    __half2 hi = __floats2half2_rn(v.z, v.w);
    u32x2 r;
    r.x = *reinterpret_cast<unsigned*>(&lo);
    r.y = *reinterpret_cast<unsigned*>(&hi);
    return r;
}
__device__ __forceinline__ f4v h4f(const __half* p) {       // 4 halfs -> 4 floats
    u32x2 u = *reinterpret_cast<const u32x2*>(p);
    unsigned a0 = u.x, a1 = u.y;
    __half2 lo = *reinterpret_cast<__half2*>(&a0);
    __half2 hi = *reinterpret_cast<__half2*>(&a1);
    float2 flo = __half22float2(lo), fhi = __half22float2(hi);
    f4v r; r.x = flo.x; r.y = flo.y; r.z = fhi.x; r.w = fhi.y;
    return r;
}
__device__ __forceinline__ float2 up2(float rawcomp) {      // 2 packed halfs -> 2 floats
    unsigned u = __float_as_uint(rawcomp);
    __half2 hh = *reinterpret_cast<__half2*>(&u);
    return __half22float2(hh);
}

// ---------------- fp16 path ----------------

// fm (fp32) -> L0' (fp16) + L1 (fp16). Thread per (L1 texel, quad q); grid (1024, 3).
__global__ __launch_bounds__(256) void mip_convert_l1(
    const float* __restrict__ fm, __half* __restrict__ wsh)
{
    int t = blockIdx.x * 256 + threadIdx.x;
    const int p = blockIdx.y;
    const int q = t & 3, idx = t >> 2;
    const int y = idx >> 8, x = idx & 255;
    const float* sp = fm + (size_t)p * FM_PLANE_STRIDE
                         + ((size_t)(2 * y) * 512 + 2 * x) * 16 + q * 4;
    f4v a = ld4nt(sp);
    f4v b = ld4nt(sp + 16);
    f4v c = ld4nt(sp + 512 * 16);
    f4v d = ld4nt(sp + 512 * 16 + 16);
    __half* L0 = wsh + (size_t)p * PSTRIDE_H;
    size_t o00 = ((size_t)(2 * y) * 512 + 2 * x) * 16 + q * 4;
    *reinterpret_cast<u32x2*>(L0 + o00)                 = pack4(a);
    *reinterpret_cast<u32x2*>(L0 + o00 + 16)            = pack4(b);
    *reinterpret_cast<u32x2*>(L0 + o00 + 512 * 16)      = pack4(c);
    *reinterpret_cast<u32x2*>(L0 + o00 + 512 * 16 + 16) = pack4(d);
    f4v m = (a + b + c + d) * 0.25f;   // L1 from fp32 source, single rounding
    __half* L1 = wsh + (size_t)p * PSTRIDE_H + (size_t)262144 * 16;
    *reinterpret_cast<u32x2*>(L1 + ((size_t)y * 256 + x) * 16 + q * 4) = pack4(m);
}

// Fused L2..L7 (fp16). Block = (32x32 L2 tile, quad q, plane p); grid (16,4,3).
__global__ __launch_bounds__(256) void mip_tail_h(__half* __restrict__ wsh)
{
    const int tile = blockIdx.x;
    const int q    = blockIdx.y;
    const int p    = blockIdx.z;
    const int ty = tile >> 2, tx = tile & 3;
    const int tid = threadIdx.x;

    __shared__ f4v A[32 * 32];
    __shared__ f4v B[16 * 16];

    __half* plane = wsh + (size_t)p * PSTRIDE_H;
    const __half* L1 = plane + (size_t)lvl_off(1) * 16;
    __half* L2 = plane + (size_t)lvl_off(2) * 16;
    __half* L3 = plane + (size_t)lvl_off(3) * 16;
    __half* L4 = plane + (size_t)lvl_off(4) * 16;
    __half* L5 = plane + (size_t)lvl_off(5) * 16;
    __half* L6 = plane + (size_t)lvl_off(6) * 16;
    __half* L7 = plane + (size_t)lvl_off(7) * 16;

    #pragma unroll
    for (int k = 0; k < 4; ++k) {
        int li = tid + k * 256;
        int ly = li >> 5, lx = li & 31;
        int gy = ty * 32 + ly, gx = tx * 32 + lx;
        const __half* sp = L1 + ((size_t)(2 * gy) * 256 + 2 * gx) * 16 + q * 4;
        f4v r = (h4f(sp) + h4f(sp + 16) + h4f(sp + 256 * 16) + h4f(sp + 256 * 16 + 16)) * 0.25f;
        A[li] = r;
        *reinterpret_cast<u32x2*>(L2 + ((size_t)gy * 128 + gx) * 16 + q * 4) = pack4(r);
    }
    __syncthreads();

    {   // L3: 16x16
        int ly = tid >> 4, lx = tid & 15;
        f4v r = (A[(2 * ly) * 32 + 2 * lx]     + A[(2 * ly) * 32 + 2 * lx + 1] +
                 A[(2 * ly + 1) * 32 + 2 * lx] + A[(2 * ly + 1) * 32 + 2 * lx + 1]) * 0.25f;
        B[tid] = r;
        *reinterpret_cast<u32x2*>(L3 + ((size_t)(ty * 16 + ly) * 64 + tx * 16 + lx) * 16 + q * 4) = pack4(r);
    }
    __syncthreads();

    if (tid < 64) {   // L4: 8x8
        int ly = tid >> 3, lx = tid & 7;
        f4v r = (B[(2 * ly) * 16 + 2 * lx]     + B[(2 * ly) * 16 + 2 * lx + 1] +
                 B[(2 * ly + 1) * 16 + 2 * lx] + B[(2 * ly + 1) * 16 + 2 * lx + 1]) * 0.25f;
        A[tid] = r;
        *reinterpret_cast<u32x2*>(L4 + ((size_t)(ty * 8 + ly) * 32 + tx * 8 + lx) * 16 + q * 4) = pack4(r);
    }
    __syncthreads();

    if (tid < 16) {   // L5: 4x4
        int ly = tid >> 2, lx = tid & 3;
        f4v r = (A[(2 * ly) * 8 + 2 * lx]     + A[(2 * ly) * 8 + 2 * lx + 1] +
                 A[(2 * ly + 1) * 8 + 2 * lx] + A[(2 * ly + 1) * 8 + 2 * lx + 1]) * 0.25f;
        B[tid] = r;
        *reinterpret_cast<u32x2*>(L5 + ((size_t)(ty * 4 + ly) * 16 + tx * 4 + lx) * 16 + q * 4) = pack4(r);
    }
    __syncthreads();

    if (tid < 4) {    // L6: 2x2
        int ly = tid >> 1, lx = tid & 1;
        f4v r = (B[(2 * ly) * 4 + 2 * lx]     + B[(2 * ly) * 4 + 2 * lx + 1] +
                 B[(2 * ly + 1) * 4 + 2 * lx] + B[(2 * ly + 1) * 4 + 2 * lx + 1]) * 0.25f;
        A[tid] = r;
        *reinterpret_cast<u32x2*>(L6 + ((size_t)(ty * 2 + ly) * 8 + tx * 2 + lx) * 16 + q * 4) = pack4(r);
    }
    __syncthreads();

    if (tid == 0) {   // L7: 1 texel
        f4v r = (A[0] + A[1] + A[2] + A[3]) * 0.25f;
        *reinterpret_cast<u32x2*>(L7 + ((size_t)ty * 4 + tx) * 16 + q * 4) = pack4(r);
    }
}

// Issue the 4 bilinear tap loads for one level WITHOUT consuming them.
// Raw q values are combined later so both levels' loads form one clause.
__device__ __forceinline__ void tap_issue(
    const __half* __restrict__ wsh, const __half* __restrict__ lds_h,
    int p, int l, float u, float v, int h,
    f4v& q00, f4v& q01, f4v& q10, f4v& q11, float& fx, float& fy)
{
    const int sz = 512 >> l;
    const float fsz = (float)sz;
    float px = u * fsz - 0.5f;
    float py = v * fsz - 0.5f;
    float xf = floorf(px), yf = floorf(py);
    fx = px - xf;
    fy = py - yf;
    int xi = (int)xf, yi = (int)yf;
    int xa = min(max(xi, 0), sz - 1);
    int xb = min(xi + 1, sz - 1);      // xi >= -1 always
    int ya = min(max(yi, 0), sz - 1);
    int yb = min(yi + 1, sz - 1);
    if (l >= 5) {
        const int sel = (l == 6) ? 256 : ((l == 7) ? 320 : 0);
        const __half* base = lds_h + (size_t)(p * 336 + sel) * 16 + h * 8;
        const __half* r0 = base + (ya * sz) * 16;
        const __half* r1 = base + (yb * sz) * 16;
        q00 = ldraw_h(r0 + xa * 16);
        q01 = ldraw_h(r0 + xb * 16);
        q10 = ldraw_h(r1 + xa * 16);
        q11 = ldraw_h(r1 + xb * 16);
    } else {
        const __half* base = wsh + (size_t)p * PSTRIDE_H + (size_t)lvl_off(l) * 16 + h * 8;
        const __half* r0 = base + (size_t)(ya * sz) * 16;
        const __half* r1 = base + (size_t)(yb * sz) * 16;
        q00 = ldraw_h(r0 + (size_t)xa * 16);
        q01 = ldraw_h(r0 + (size_t)xb * 16);
        q10 = ldraw_h(r1 + (size_t)xa * 16);
        q11 = ldraw_h(r1 + (size_t)xb * 16);
    }
}

// One thread per (point n, plane p, half h): t = (n*3 + p)*2 + h.
// Block 512; LDS holds levels 5..7 of all 3 planes (31.5 KB).
// launch_bounds(512, 8): 8 waves/EU -> 4 blocks/CU; caps VGPR so the
// 8-deep tap clause cannot halve occupancy.
__global__ __launch_bounds__(512, 8) void trimip_sample_h(
    const float* __restrict__ xyz, const float* __restrict__ level,
    const __half* __restrict__ wsh, float* __restrict__ out, int N)
{
    __shared__ u32x4 lds[2016];       // 3 planes * 336 texels * 32 B = 32256 B
    for (int uidx = threadIdx.x; uidx < 2016; uidx += 512) {
        int p = uidx / 672;           // 672 16-B units per plane
        int rem = uidx - p * 672;
        lds[uidx] = *reinterpret_cast<const u32x4*>(
            wsh + (size_t)p * PSTRIDE_H + (size_t)LVL5_OFF * 16 + (size_t)rem * 8);
    }
    __syncthreads();
    const __half* lds_h = reinterpret_cast<const __half*>(lds);

    int t = blockIdx.x * 512 + threadIdx.x;
    if (t >= N * 6) return;
    const int h = t & 1;
    const int r = t >> 1;
    const int n = r / 3;
    const int p = r - n * 3;

    const float c0 = xyz[n * 3 + 0];
    const float c1 = xyz[n * 3 + 1];
    const float c2 = xyz[n * 3 + 2];
    const float u = (p == 0) ? c1 : c0;
    const float v = (p == 2) ? c1 : c2;

    float lv = level[n];
    lv = fminf(fmaxf(lv, 0.f), 7.f);
    float lf = floorf(lv);
    float f = lv - lf;
    int l0 = (int)lf;
    int l1 = min(l0 + 1, 7);

    // Issue ALL 8 tap loads before consuming any (single clause; compiler
    // waits vmcnt(4) before the l0 combine, vmcnt(0) before the l1 one).
    f4v a00, a01, a10, a11, b00, b01, b10, b11;
    float fx0, fy0, fx1, fy1;
    tap_issue(wsh, lds_h, p, l0, u, v, h, a00, a01, a10, a11, fx0, fy0);
    tap_issue(wsh, lds_h, p, l1, u, v, h, b00, b01, b10, b11, fx1, fy1);

    float s0[8], s1[8];
    {
        float gx = 1.f - fx0, gy = 1.f - fy0;
        float w00 = gx * gy, w01 = fx0 * gy, w10 = gx * fy0, w11 = fx0 * fy0;
        #pragma unroll
        for (int i = 0; i < 4; ++i) {
            float2 a = up2(a00[i]), b = up2(a01[i]), c = up2(a10[i]), d = up2(a11[i]);
            s0[2 * i]     = a.x * w00 + b.x * w01 + c.x * w10 + d.x * w11;
            s0[2 * i + 1] = a.y * w00 + b.y * w01 + c.y * w10 + d.y * w11;
        }
    }
    {
        float gx = 1.f - fx1, gy = 1.f - fy1;
        float w00 = gx * gy, w01 = fx1 * gy, w10 = gx * fy1, w11 = fx1 * fy1;
        #pragma unroll
        for (int i = 0; i < 4; ++i) {
            float2 a = up2(b00[i]), b = up2(b01[i]), c = up2(b10[i]), d = up2(b11[i]);
            s1[2 * i]     = a.x * w00 + b.x * w01 + c.x * w10 + d.x * w11;
            s1[2 * i + 1] = a.y * w00 + b.y * w01 + c.y * w10 + d.y * w11;
        }
    }

    float g = 1.f - f;
    f4v oa, ob;
    #pragma unroll
    for (int i = 0; i < 4; ++i) {
        oa[i] = s0[i] * g + s1[i] * f;
        ob[i] = s0[4 + i] * g + s1[4 + i] * f;
    }
    st4nt(out + (size_t)t * 8, oa);
    st4nt(out + (size_t)t * 8 + 4, ob);
}

// ---------------- fp32 fallback path ----------------

__device__ __forceinline__ f4v avg4(f4v a, f4v b, f4v c, f4v d) {
    return (a + b + c + d) * 0.25f;
}

__global__ __launch_bounds__(256) void mip_build_f(
    const float* __restrict__ src, float* __restrict__ dst)
{
    int t = blockIdx.x * blockDim.x + threadIdx.x;
    const int p = blockIdx.y;
    const int q = t & 3, idx = t >> 2;
    const int y = idx >> 8, x = idx & 255;
    const float* sp = src + (size_t)p * FM_PLANE_STRIDE
                          + ((size_t)(2 * y) * 512 + 2 * x) * 16 + q * 4;
    f4v r = avg4(ld4(sp), ld4(sp + 16), ld4(sp + 512 * 16), ld4(sp + 512 * 16 + 16));
    st4(dst + (size_t)p * WS_PLANE_STRIDE + ((size_t)y * 256 + x) * 16 + q * 4, r);
}

__global__ __launch_bounds__(256) void mip_tail_f(float* __restrict__ mips)
{
    const int tile = blockIdx.x, q = blockIdx.y, p = blockIdx.z;
    const int ty = tile >> 2, tx = tile & 3;
    const int tid = threadIdx.x;
    __shared__ f4v A[32 * 32];
    __shared__ f4v B[16 * 16];
    float* plane = mips + (size_t)p * WS_PLANE_STRIDE;
    const float* L1 = plane;
    float* L2 = plane + (size_t)65536 * 16;
    float* L3 = plane + (size_t)81920 * 16;
    float* L4 = plane + (size_t)86016 * 16;
    float* L5 = plane + (size_t)87040 * 16;
    float* L6 = plane + (size_t)87296 * 16;
    float* L7 = plane + (size_t)87360 * 16;

    #pragma unroll
    for (int k = 0; k < 4; ++k) {
        int li = tid + k * 256;
        int ly = li >> 5, lx = li & 31;
        int gy = ty * 32 + ly, gx = tx * 32 + lx;
        const float* sp = L1 + ((size_t)(2 * gy) * 256 + 2 * gx) * 16 + q * 4;
        f4v r = avg4(ld4(sp), ld4(sp + 16), ld4(sp + 256 * 16), ld4(sp + 256 * 16 + 16));
        A[li] = r;
        st4(L2 + ((size_t)gy * 128 + gx) * 16 + q * 4, r);
    }
    __syncthreads();
    {
        int ly = tid >> 4, lx = tid & 15;
        f4v r = avg4(A[(2 * ly) * 32 + 2 * lx],     A[(2 * ly) * 32 + 2 * lx + 1],
                     A[(2 * ly + 1) * 32 + 2 * lx], A[(2 * ly + 1) * 32 + 2 * lx + 1]);
        B[tid] = r;
        st4(L3 + ((size_t)(ty * 16 + ly) * 64 + tx * 16 + lx) * 16 + q * 4, r);
    }
    __syncthreads();
    if (tid < 64) {
        int ly = tid >> 3, lx = tid & 7;
        f4v r = avg4(B[(2 * ly) * 16 + 2 * lx],     B[(2 * ly) * 16 + 2 * lx + 1],
                     B[(2 * ly + 1) * 16 + 2 * lx], B[(2 * ly + 1) * 16 + 2 * lx + 1]);
        A[tid] = r;
        st4(L4 + ((size_t)(ty * 8 + ly) * 32 + tx * 8 + lx) * 16 + q * 4, r);
    }
    __syncthreads();
    if (tid < 16) {
        int ly = tid >> 2, lx = tid & 3;
        f4v r = avg4(A[(2 * ly) * 8 + 2 * lx],     A[(2 * ly) * 8 + 2 * lx + 1],
                     A[(2 * ly + 1) * 8 + 2 * lx], A[(2 * ly + 1) * 8 + 2 * lx + 1]);
        B[tid] = r;
        st4(L5 + ((size_t)(ty * 4 + ly) * 16 + tx * 4 + lx) * 16 + q * 4, r);
    }
    __syncthreads();
    if (tid < 4) {
        int ly = tid >> 1, lx = tid & 1;
        f4v r = avg4(B[(2 * ly) * 4 + 2 * lx],     B[(2 * ly) * 4 + 2 * lx + 1],
                     B[(2 * ly + 1) * 4 + 2 * lx], B[(2 * ly + 1) * 4 + 2 * lx + 1]);
        A[tid] = r;
        st4(L6 + ((size_t)(ty * 2 + ly) * 8 + tx * 2 + lx) * 16 + q * 4, r);
    }
    __syncthreads();
    if (tid == 0) {
        f4v r = avg4(A[0], A[1], A[2], A[3]);
        st4(L7 + ((size_t)ty * 4 + tx) * 16 + q * 4, r);
    }
}

__device__ __forceinline__ f4v bilerp_f(
    const float* __restrict__ fm, const float* __restrict__ mips,
    int p, int l, float u, float v, int q)
{
    const int sz = 512 >> l;
    const float fsz = (float)sz;
    float px = u * fsz - 0.5f;
    float py = v * fsz - 0.5f;
    float xf = floorf(px), yf = floorf(py);
    float fx = px - xf, fy = py - yf;
    int xi = (int)xf, yi = (int)yf;
    int xa = min(max(xi, 0), sz - 1);
    int xb = min(xi + 1, sz - 1);
    int ya = min(max(yi, 0), sz - 1);
    int yb = min(yi + 1, sz - 1);
    const float* base;
    if (l == 0) {
        base = fm + (size_t)p * FM_PLANE_STRIDE;
    } else {
        unsigned off = (262144u - ((unsigned)(sz * sz) << 2)) / 3u;
        base = mips + (size_t)p * WS_PLANE_STRIDE + (size_t)off * 16;
    }
    const float* r0 = base + (size_t)(ya * sz) * 16 + q * 4;
    const float* r1 = base + (size_t)(yb * sz) * 16 + q * 4;
    f4v f00 = ld4(r0 + xa * 16);
    f4v f01 = ld4(r0 + xb * 16);
    f4v f10 = ld4(r1 + xa * 16);
    f4v f11 = ld4(r1 + xb * 16);
    float gx = 1.f - fx, gy = 1.f - fy;
    return (f00 * gx + f01 * fx) * gy + (f10 * gx + f11 * fx) * fy;
}

__global__ __launch_bounds__(256) void trimip_sample_f(
    const float* __restrict__ xyz, const float* __restrict__ level,
    const float* __restrict__ fm, const float* __restrict__ mips,
    float* __restrict__ out, int N)
{
    int t = blockIdx.x * blockDim.x + threadIdx.x;
    if (t >= N * 12) return;
    const int q = t & 3;
    const int r = t >> 2;
    const int n = r / 3;
    const int p = r - n * 3;
    const float c0 = xyz[n * 3 + 0];
    const float c1 = xyz[n * 3 + 1];
    const float c2 = xyz[n * 3 + 2];
    const float u = (p == 0) ? c1 : c0;
    const float v = (p == 2) ? c1 : c2;
    float lv = level[n];
    lv = fminf(fmaxf(lv, 0.f), 7.f);
    float lf = floorf(lv);
    float f = lv - lf;
    int l0 = (int)lf;
    int l1 = min(l0 + 1, 7);
    f4v s0 = bilerp_f(fm, mips, p, l0, u, v, q);
    f4v s1 = bilerp_f(fm, mips, p, l1, u, v, q);
    f4v o = s0 * (1.f - f) + s1 * f;
    st4nt(out + (size_t)t * 4, o);
}

extern "C" void kernel_launch(void* const* d_in, const int* in_sizes, int n_in,
                              void* d_out, int out_size, void* d_ws, size_t ws_size,
                              hipStream_t stream) {
    const float* xyz   = (const float*)d_in[0];
    const float* level = (const float*)d_in[1];
    const float* fm    = (const float*)d_in[2];
    float* out = (float*)d_out;
    const int N = in_sizes[1];

    if (ws_size >= WS_H_BYTES) {
        __half* wsh = (__half*)d_ws;
        mip_convert_l1<<<dim3(1024, 3), dim3(256), 0, stream>>>(fm, wsh);
        mip_tail_h<<<dim3(16, 4, 3), dim3(256), 0, stream>>>(wsh);
        const int total = N * 6;
        trimip_sample_h<<<(total + 511) / 512, 512, 0, stream>>>(xyz, level, wsh, out, N);
    } else {
        float* mips = (float*)d_ws;
        mip_build_f<<<dim3(1024, 3), dim3(256), 0, stream>>>(fm, mips);
        mip_tail_f<<<dim3(16, 4, 3), dim3(256), 0, stream>>>(mips);
        const int total = N * 12;
        trimip_sample_f<<<(total + 255) / 256, 256, 0, stream>>>(xyz, level, fm, mips, out, N);
    }
}

// Round 5
// 197.744 us; speedup vs baseline: 1.2163x; 1.0152x over previous
//
#include <hip/hip_runtime.h>
#include <hip/hip_fp16.h>

// TriMipEncoding: N pts, 3 planes (512^2, 16 ch), 8 mip levels, trilinear sample.
//
// Fast path (ws_size >= 33.6 MB): full fp16 pyramid (levels 0..7) in d_ws.
//   Texel = 16 halfs = 32 B. Per-plane texel offset of level l:
//   off(l) = (2^20 - (2^20 >> 2l)) / 3. Plane stride = 349520 texels.
// R3: sampler duration identical at FETCH=0 vs FETCH=122MB -> NOT HBM-bound.
// R4: stage levels 5..7 (31.5 KB, all planes) in LDS -> real win (~36%).
// R5 FAILED (1 thread/pt): broke store coalescing + occupancy -> 2.3x.
// R6 NEUTRAL: broadcast xyz/level loads are free (TA handles wave-uniform
//   addresses in ~1 cy) -- only falsifies broadcast-address cost.
// R7 NEUTRAL: level-uniform waves (instr count halved) changed nothing.
// R8 NEUTRAL: single 8-load clause (per-thread MLP) changed nothing.
// Surviving model: DIVERGENT global lane-request rate through the vmem
//   pipe (~50/pt ~= 66 us at ~1/cy/CU). Only lever: move taps to the
//   slack LDS pipe (what worked in R4).
// R9 (this round): one plane per block (blockIdx.y=p), 2 threads/pt;
//   LDS stages that plane's levels 4..7 (1360 texels, 42.5 KB -> 3
//   blocks/CU, 24 waves/CU). Global tap-sets/pt: 9/7 -> 7/7 (-22%
//   divergent global lane-requests). Output bytes/addressing unchanged
//   (64B-aligned chunk per (n,p), fully covered by the h-pair's adjacent
//   stores). If neutral: model space exhausted -> gather-rate roofline.

typedef float        f4v   __attribute__((ext_vector_type(4)));
typedef unsigned int u32x2 __attribute__((ext_vector_type(2)));
typedef unsigned int u32x4 __attribute__((ext_vector_type(4)));

#define FM_PLANE_STRIDE (262144 * 16)   // floats per plane in fm
#define WS_PLANE_STRIDE (87376 * 16)    // floats per plane, fp32 fallback pyramid
#define PSTRIDE_H (349520 * 16)         // halfs per plane, fp16 full pyramid
#define WS_H_BYTES (3ull * PSTRIDE_H * 2ull)
#define LVL4_OFF 348160u                // texel offset of level 4 (levels 4..7 contiguous)

__device__ __forceinline__ unsigned lvl_off(int l) {   // texel offset of level l
    return (1048576u - (1048576u >> (2 * l))) / 3u;
}

__device__ __forceinline__ f4v ld4(const float* p) {
    return *reinterpret_cast<const f4v*>(p);
}
__device__ __forceinline__ f4v ld4nt(const float* p) {
    return __builtin_nontemporal_load(reinterpret_cast<const f4v*>(p));
}
__device__ __forceinline__ void st4(float* p, f4v v) {
    *reinterpret_cast<f4v*>(p) = v;
}
__device__ __forceinline__ void st4nt(float* p, f4v v) {
    __builtin_nontemporal_store(v, reinterpret_cast<f4v*>(p));
}
__device__ __forceinline__ f4v ldraw_h(const __half* p) {   // 8 halfs as raw f4v
    return *reinterpret_cast<const f4v*>(p);
}
__device__ __forceinline__ u32x2 pack4(f4v v) {             // 4 floats -> 4 halfs
    __half2 lo = __floats2half2_rn(v.x, v.y);
    __half2 hi = __floats2half2_rn(v.z, v.w);
    u32x2 r;
    r.x = *reinterpret_cast<unsigned*>(&lo);
    r.y = *reinterpret_cast<unsigned*>(&hi);
    return r;
}
__device__ __forceinline__ f4v h4f(const __half* p) {       // 4 halfs -> 4 floats
    u32x2 u = *reinterpret_cast<const u32x2*>(p);
    unsigned a0 = u.x, a1 = u.y;
    __half2 lo = *reinterpret_cast<__half2*>(&a0);
    __half2 hi = *reinterpret_cast<__half2*>(&a1);
    float2 flo = __half22float2(lo), fhi = __half22float2(hi);
    f4v r; r.x = flo.x; r.y = flo.y; r.z = fhi.x; r.w = fhi.y;
    return r;
}
__device__ __forceinline__ float2 up2(float rawcomp) {      // 2 packed halfs -> 2 floats
    unsigned u = __float_as_uint(rawcomp);
    __half2 hh = *reinterpret_cast<__half2*>(&u);
    return __half22float2(hh);
}

// ---------------- fp16 path ----------------

// fm (fp32) -> L0' (fp16) + L1 (fp16). Thread per (L1 texel, quad q); grid (1024, 3).
__global__ __launch_bounds__(256) void mip_convert_l1(
    const float* __restrict__ fm, __half* __restrict__ wsh)
{
    int t = blockIdx.x * 256 + threadIdx.x;
    const int p = blockIdx.y;
    const int q = t & 3, idx = t >> 2;
    const int y = idx >> 8, x = idx & 255;
    const float* sp = fm + (size_t)p * FM_PLANE_STRIDE
                         + ((size_t)(2 * y) * 512 + 2 * x) * 16 + q * 4;
    f4v a = ld4nt(sp);
    f4v b = ld4nt(sp + 16);
    f4v c = ld4nt(sp + 512 * 16);
    f4v d = ld4nt(sp + 512 * 16 + 16);
    __half* L0 = wsh + (size_t)p * PSTRIDE_H;
    size_t o00 = ((size_t)(2 * y) * 512 + 2 * x) * 16 + q * 4;
    *reinterpret_cast<u32x2*>(L0 + o00)                 = pack4(a);
    *reinterpret_cast<u32x2*>(L0 + o00 + 16)            = pack4(b);
    *reinterpret_cast<u32x2*>(L0 + o00 + 512 * 16)      = pack4(c);
    *reinterpret_cast<u32x2*>(L0 + o00 + 512 * 16 + 16) = pack4(d);
    f4v m = (a + b + c + d) * 0.25f;   // L1 from fp32 source, single rounding
    __half* L1 = wsh + (size_t)p * PSTRIDE_H + (size_t)262144 * 16;
    *reinterpret_cast<u32x2*>(L1 + ((size_t)y * 256 + x) * 16 + q * 4) = pack4(m);
}

// Fused L2..L7 (fp16). Block = (32x32 L2 tile, quad q, plane p); grid (16,4,3).
__global__ __launch_bounds__(256) void mip_tail_h(__half* __restrict__ wsh)
{
    const int tile = blockIdx.x;
    const int q    = blockIdx.y;
    const int p    = blockIdx.z;
    const int ty = tile >> 2, tx = tile & 3;
    const int tid = threadIdx.x;

    __shared__ f4v A[32 * 32];
    __shared__ f4v B[16 * 16];

    __half* plane = wsh + (size_t)p * PSTRIDE_H;
    const __half* L1 = plane + (size_t)lvl_off(1) * 16;
    __half* L2 = plane + (size_t)lvl_off(2) * 16;
    __half* L3 = plane + (size_t)lvl_off(3) * 16;
    __half* L4 = plane + (size_t)lvl_off(4) * 16;
    __half* L5 = plane + (size_t)lvl_off(5) * 16;
    __half* L6 = plane + (size_t)lvl_off(6) * 16;
    __half* L7 = plane + (size_t)lvl_off(7) * 16;

    #pragma unroll
    for (int k = 0; k < 4; ++k) {
        int li = tid + k * 256;
        int ly = li >> 5, lx = li & 31;
        int gy = ty * 32 + ly, gx = tx * 32 + lx;
        const __half* sp = L1 + ((size_t)(2 * gy) * 256 + 2 * gx) * 16 + q * 4;
        f4v r = (h4f(sp) + h4f(sp + 16) + h4f(sp + 256 * 16) + h4f(sp + 256 * 16 + 16)) * 0.25f;
        A[li] = r;
        *reinterpret_cast<u32x2*>(L2 + ((size_t)gy * 128 + gx) * 16 + q * 4) = pack4(r);
    }
    __syncthreads();

    {   // L3: 16x16
        int ly = tid >> 4, lx = tid & 15;
        f4v r = (A[(2 * ly) * 32 + 2 * lx]     + A[(2 * ly) * 32 + 2 * lx + 1] +
                 A[(2 * ly + 1) * 32 + 2 * lx] + A[(2 * ly + 1) * 32 + 2 * lx + 1]) * 0.25f;
        B[tid] = r;
        *reinterpret_cast<u32x2*>(L3 + ((size_t)(ty * 16 + ly) * 64 + tx * 16 + lx) * 16 + q * 4) = pack4(r);
    }
    __syncthreads();

    if (tid < 64) {   // L4: 8x8
        int ly = tid >> 3, lx = tid & 7;
        f4v r = (B[(2 * ly) * 16 + 2 * lx]     + B[(2 * ly) * 16 + 2 * lx + 1] +
                 B[(2 * ly + 1) * 16 + 2 * lx] + B[(2 * ly + 1) * 16 + 2 * lx + 1]) * 0.25f;
        A[tid] = r;
        *reinterpret_cast<u32x2*>(L4 + ((size_t)(ty * 8 + ly) * 32 + tx * 8 + lx) * 16 + q * 4) = pack4(r);
    }
    __syncthreads();

    if (tid < 16) {   // L5: 4x4
        int ly = tid >> 2, lx = tid & 3;
        f4v r = (A[(2 * ly) * 8 + 2 * lx]     + A[(2 * ly) * 8 + 2 * lx + 1] +
                 A[(2 * ly + 1) * 8 + 2 * lx] + A[(2 * ly + 1) * 8 + 2 * lx + 1]) * 0.25f;
        B[tid] = r;
        *reinterpret_cast<u32x2*>(L5 + ((size_t)(ty * 4 + ly) * 16 + tx * 4 + lx) * 16 + q * 4) = pack4(r);
    }
    __syncthreads();

    if (tid < 4) {    // L6: 2x2
        int ly = tid >> 1, lx = tid & 1;
        f4v r = (B[(2 * ly) * 4 + 2 * lx]     + B[(2 * ly) * 4 + 2 * lx + 1] +
                 B[(2 * ly + 1) * 4 + 2 * lx] + B[(2 * ly + 1) * 4 + 2 * lx + 1]) * 0.25f;
        A[tid] = r;
        *reinterpret_cast<u32x2*>(L6 + ((size_t)(ty * 2 + ly) * 8 + tx * 2 + lx) * 16 + q * 4) = pack4(r);
    }
    __syncthreads();

    if (tid == 0) {   // L7: 1 texel
        f4v r = (A[0] + A[1] + A[2] + A[3]) * 0.25f;
        *reinterpret_cast<u32x2*>(L7 + ((size_t)ty * 4 + tx) * 16 + q * 4) = pack4(r);
    }
}

// Issue the 4 bilinear tap loads for one level WITHOUT consuming them.
// wplane = fp16 pyramid base of this block's plane. Levels >= 4 read the
// LDS copy (this plane's levels 4..7 staged linearly from texel LVL4_OFF).
__device__ __forceinline__ void tap_issue(
    const __half* __restrict__ wplane, const __half* __restrict__ lds_h,
    int l, float u, float v, int h,
    f4v& q00, f4v& q01, f4v& q10, f4v& q11, float& fx, float& fy)
{
    const int sz = 512 >> l;
    const float fsz = (float)sz;
    float px = u * fsz - 0.5f;
    float py = v * fsz - 0.5f;
    float xf = floorf(px), yf = floorf(py);
    fx = px - xf;
    fy = py - yf;
    int xi = (int)xf, yi = (int)yf;
    int xa = min(max(xi, 0), sz - 1);
    int xb = min(xi + 1, sz - 1);      // xi >= -1 always
    int ya = min(max(yi, 0), sz - 1);
    int yb = min(yi + 1, sz - 1);
    if (l >= 4) {
        const __half* base = lds_h + (size_t)(lvl_off(l) - LVL4_OFF) * 16 + h * 8;
        const __half* r0 = base + (ya * sz) * 16;
        const __half* r1 = base + (yb * sz) * 16;
        q00 = ldraw_h(r0 + xa * 16);
        q01 = ldraw_h(r0 + xb * 16);
        q10 = ldraw_h(r1 + xa * 16);
        q11 = ldraw_h(r1 + xb * 16);
    } else {
        const __half* base = wplane + (size_t)lvl_off(l) * 16 + h * 8;
        const __half* r0 = base + (size_t)(ya * sz) * 16;
        const __half* r1 = base + (size_t)(yb * sz) * 16;
        q00 = ldraw_h(r0 + (size_t)xa * 16);
        q01 = ldraw_h(r0 + (size_t)xb * 16);
        q10 = ldraw_h(r1 + (size_t)xa * 16);
        q11 = ldraw_h(r1 + (size_t)xb * 16);
    }
}

// One plane per block (blockIdx.y = p); 2 threads per point (h = tid&1),
// 256 points per 512-thread block. LDS: this plane's levels 4..7
// (1360 texels * 32 B = 42.5 KB -> 3 blocks/CU, 24 waves/CU).
__global__ __launch_bounds__(512) void trimip_sample_h(
    const float* __restrict__ xyz, const float* __restrict__ level,
    const __half* __restrict__ wsh, float* __restrict__ out, int N)
{
    __shared__ u32x4 lds[2720];       // 1360 texels * 32 B
    const int p = blockIdx.y;
    const __half* wplane = wsh + (size_t)p * PSTRIDE_H;
    for (int uidx = threadIdx.x; uidx < 2720; uidx += 512) {
        lds[uidx] = *reinterpret_cast<const u32x4*>(
            wplane + (size_t)LVL4_OFF * 16 + (size_t)uidx * 8);
    }
    __syncthreads();
    const __half* lds_h = reinterpret_cast<const __half*>(lds);

    const int n = blockIdx.x * 256 + (threadIdx.x >> 1);
    if (n >= N) return;
    const int h = threadIdx.x & 1;

    const float c0 = xyz[n * 3 + 0];
    const float c1 = xyz[n * 3 + 1];
    const float c2 = xyz[n * 3 + 2];
    const float u = (p == 0) ? c1 : c0;
    const float v = (p == 2) ? c1 : c2;

    float lv = level[n];
    lv = fminf(fmaxf(lv, 0.f), 7.f);
    float lf = floorf(lv);
    float f = lv - lf;
    int l0 = (int)lf;
    int l1 = min(l0 + 1, 7);

    // Issue all 8 tap loads before consuming any.
    f4v a00, a01, a10, a11, b00, b01, b10, b11;
    float fx0, fy0, fx1, fy1;
    tap_issue(wplane, lds_h, l0, u, v, h, a00, a01, a10, a11, fx0, fy0);
    tap_issue(wplane, lds_h, l1, u, v, h, b00, b01, b10, b11, fx1, fy1);

    float s0[8], s1[8];
    {
        float gx = 1.f - fx0, gy = 1.f - fy0;
        float w00 = gx * gy, w01 = fx0 * gy, w10 = gx * fy0, w11 = fx0 * fy0;
        #pragma unroll
        for (int i = 0; i < 4; ++i) {
            float2 a = up2(a00[i]), b = up2(a01[i]), c = up2(a10[i]), d = up2(a11[i]);
            s0[2 * i]     = a.x * w00 + b.x * w01 + c.x * w10 + d.x * w11;
            s0[2 * i + 1] = a.y * w00 + b.y * w01 + c.y * w10 + d.y * w11;
        }
    }
    {
        float gx = 1.f - fx1, gy = 1.f - fy1;
        float w00 = gx * gy, w01 = fx1 * gy, w10 = gx * fy1, w11 = fx1 * fy1;
        #pragma unroll
        for (int i = 0; i < 4; ++i) {
            float2 a = up2(b00[i]), b = up2(b01[i]), c = up2(b10[i]), d = up2(b11[i]);
            s1[2 * i]     = a.x * w00 + b.x * w01 + c.x * w10 + d.x * w11;
            s1[2 * i + 1] = a.y * w00 + b.y * w01 + c.y * w10 + d.y * w11;
        }
    }

    float g = 1.f - f;
    f4v oa, ob;
    #pragma unroll
    for (int i = 0; i < 4; ++i) {
        oa[i] = s0[i] * g + s1[i] * f;
        ob[i] = s0[4 + i] * g + s1[4 + i] * f;
    }
    float* op = out + (size_t)((n * 3 + p) * 2 + h) * 8;
    st4nt(op, oa);
    st4nt(op + 4, ob);
}

// ---------------- fp32 fallback path ----------------

__device__ __forceinline__ f4v avg4(f4v a, f4v b, f4v c, f4v d) {
    return (a + b + c + d) * 0.25f;
}

__global__ __launch_bounds__(256) void mip_build_f(
    const float* __restrict__ src, float* __restrict__ dst)
{
    int t = blockIdx.x * blockDim.x + threadIdx.x;
    const int p = blockIdx.y;
    const int q = t & 3, idx = t >> 2;
    const int y = idx >> 8, x = idx & 255;
    const float* sp = src + (size_t)p * FM_PLANE_STRIDE
                          + ((size_t)(2 * y) * 512 + 2 * x) * 16 + q * 4;
    f4v r = avg4(ld4(sp), ld4(sp + 16), ld4(sp + 512 * 16), ld4(sp + 512 * 16 + 16));
    st4(dst + (size_t)p * WS_PLANE_STRIDE + ((size_t)y * 256 + x) * 16 + q * 4, r);
}

__global__ __launch_bounds__(256) void mip_tail_f(float* __restrict__ mips)
{
    const int tile = blockIdx.x, q = blockIdx.y, p = blockIdx.z;
    const int ty = tile >> 2, tx = tile & 3;
    const int tid = threadIdx.x;
    __shared__ f4v A[32 * 32];
    __shared__ f4v B[16 * 16];
    float* plane = mips + (size_t)p * WS_PLANE_STRIDE;
    const float* L1 = plane;
    float* L2 = plane + (size_t)65536 * 16;
    float* L3 = plane + (size_t)81920 * 16;
    float* L4 = plane + (size_t)86016 * 16;
    float* L5 = plane + (size_t)87040 * 16;
    float* L6 = plane + (size_t)87296 * 16;
    float* L7 = plane + (size_t)87360 * 16;

    #pragma unroll
    for (int k = 0; k < 4; ++k) {
        int li = tid + k * 256;
        int ly = li >> 5, lx = li & 31;
        int gy = ty * 32 + ly, gx = tx * 32 + lx;
        const float* sp = L1 + ((size_t)(2 * gy) * 256 + 2 * gx) * 16 + q * 4;
        f4v r = avg4(ld4(sp), ld4(sp + 16), ld4(sp + 256 * 16), ld4(sp + 256 * 16 + 16));
        A[li] = r;
        st4(L2 + ((size_t)gy * 128 + gx) * 16 + q * 4, r);
    }
    __syncthreads();
    {
        int ly = tid >> 4, lx = tid & 15;
        f4v r = avg4(A[(2 * ly) * 32 + 2 * lx],     A[(2 * ly) * 32 + 2 * lx + 1],
                     A[(2 * ly + 1) * 32 + 2 * lx], A[(2 * ly + 1) * 32 + 2 * lx + 1]);
        B[tid] = r;
        st4(L3 + ((size_t)(ty * 16 + ly) * 64 + tx * 16 + lx) * 16 + q * 4, r);
    }
    __syncthreads();
    if (tid < 64) {
        int ly = tid >> 3, lx = tid & 7;
        f4v r = avg4(B[(2 * ly) * 16 + 2 * lx],     B[(2 * ly) * 16 + 2 * lx + 1],
                     B[(2 * ly + 1) * 16 + 2 * lx], B[(2 * ly + 1) * 16 + 2 * lx + 1]);
        A[tid] = r;
        st4(L4 + ((size_t)(ty * 8 + ly) * 32 + tx * 8 + lx) * 16 + q * 4, r);
    }
    __syncthreads();
    if (tid < 16) {
        int ly = tid >> 2, lx = tid & 3;
        f4v r = avg4(A[(2 * ly) * 8 + 2 * lx],     A[(2 * ly) * 8 + 2 * lx + 1],
                     A[(2 * ly + 1) * 8 + 2 * lx], A[(2 * ly + 1) * 8 + 2 * lx + 1]);
        B[tid] = r;
        st4(L5 + ((size_t)(ty * 4 + ly) * 16 + tx * 4 + lx) * 16 + q * 4, r);
    }
    __syncthreads();
    if (tid < 4) {
        int ly = tid >> 1, lx = tid & 1;
        f4v r = avg4(B[(2 * ly) * 4 + 2 * lx],     B[(2 * ly) * 4 + 2 * lx + 1],
                     B[(2 * ly + 1) * 4 + 2 * lx], B[(2 * ly + 1) * 4 + 2 * lx + 1]);
        A[tid] = r;
        st4(L6 + ((size_t)(ty * 2 + ly) * 8 + tx * 2 + lx) * 16 + q * 4, r);
    }
    __syncthreads();
    if (tid == 0) {
        f4v r = avg4(A[0], A[1], A[2], A[3]);
        st4(L7 + ((size_t)ty * 4 + tx) * 16 + q * 4, r);
    }
}

__device__ __forceinline__ f4v bilerp_f(
    const float* __restrict__ fm, const float* __restrict__ mips,
    int p, int l, float u, float v, int q)
{
    const int sz = 512 >> l;
    const float fsz = (float)sz;
    float px = u * fsz - 0.5f;
    float py = v * fsz - 0.5f;
    float xf = floorf(px), yf = floorf(py);
    float fx = px - xf, fy = py - yf;
    int xi = (int)xf, yi = (int)yf;
    int xa = min(max(xi, 0), sz - 1);
    int xb = min(xi + 1, sz - 1);
    int ya = min(max(yi, 0), sz - 1);
    int yb = min(yi + 1, sz - 1);
    const float* base;
    if (l == 0) {
        base = fm + (size_t)p * FM_PLANE_STRIDE;
    } else {
        unsigned off = (262144u - ((unsigned)(sz * sz) << 2)) / 3u;
        base = mips + (size_t)p * WS_PLANE_STRIDE + (size_t)off * 16;
    }
    const float* r0 = base + (size_t)(ya * sz) * 16 + q * 4;
    const float* r1 = base + (size_t)(yb * sz) * 16 + q * 4;
    f4v f00 = ld4(r0 + xa * 16);
    f4v f01 = ld4(r0 + xb * 16);
    f4v f10 = ld4(r1 + xa * 16);
    f4v f11 = ld4(r1 + xb * 16);
    float gx = 1.f - fx, gy = 1.f - fy;
    return (f00 * gx + f01 * fx) * gy + (f10 * gx + f11 * fx) * fy;
}

__global__ __launch_bounds__(256) void trimip_sample_f(
    const float* __restrict__ xyz, const float* __restrict__ level,
    const float* __restrict__ fm, const float* __restrict__ mips,
    float* __restrict__ out, int N)
{
    int t = blockIdx.x * blockDim.x + threadIdx.x;
    if (t >= N * 12) return;
    const int q = t & 3;
    const int r = t >> 2;
    const int n = r / 3;
    const int p = r - n * 3;
    const float c0 = xyz[n * 3 + 0];
    const float c1 = xyz[n * 3 + 1];
    const float c2 = xyz[n * 3 + 2];
    const float u = (p == 0) ? c1 : c0;
    const float v = (p == 2) ? c1 : c2;
    float lv = level[n];
    lv = fminf(fmaxf(lv, 0.f), 7.f);
    float lf = floorf(lv);
    float f = lv - lf;
    int l0 = (int)lf;
    int l1 = min(l0 + 1, 7);
    f4v s0 = bilerp_f(fm, mips, p, l0, u, v, q);
    f4v s1 = bilerp_f(fm, mips, p, l1, u, v, q);
    f4v o = s0 * (1.f - f) + s1 * f;
    st4nt(out + (size_t)t * 4, o);
}

extern "C" void kernel_launch(void* const* d_in, const int* in_sizes, int n_in,
                              void* d_out, int out_size, void* d_ws, size_t ws_size,
                              hipStream_t stream) {
    const float* xyz   = (const float*)d_in[0];
    const float* level = (const float*)d_in[1];
    const float* fm    = (const float*)d_in[2];
    float* out = (float*)d_out;
    const int N = in_sizes[1];

    if (ws_size >= WS_H_BYTES) {
        __half* wsh = (__half*)d_ws;
        mip_convert_l1<<<dim3(1024, 3), dim3(256), 0, stream>>>(fm, wsh);
        mip_tail_h<<<dim3(16, 4, 3), dim3(256), 0, stream>>>(wsh);
        trimip_sample_h<<<dim3((N + 255) / 256, 3), 512, 0, stream>>>(
            xyz, level, wsh, out, N);
    } else {
        float* mips = (float*)d_ws;
        mip_build_f<<<dim3(1024, 3), dim3(256), 0, stream>>>(fm, mips);
        mip_tail_f<<<dim3(16, 4, 3), dim3(256), 0, stream>>>(mips);
        const int total = N * 12;
        trimip_sample_f<<<(total + 255) / 256, 256, 0, stream>>>(xyz, level, fm, mips, out, N);
    }
}

// Round 6
// 196.381 us; speedup vs baseline: 1.2247x; 1.0069x over previous
//
#include <hip/hip_runtime.h>
#include <hip/hip_fp16.h>

// TriMipEncoding: N pts, 3 planes (512^2, 16 ch), 8 mip levels, trilinear sample.
//
// Fast path (ws_size >= 33.6 MB): full fp16 pyramid (levels 0..7) in d_ws.
//   Texel = 16 halfs = 32 B. Per-plane texel offset of level l:
//   off(l) = (2^20 - (2^20 >> 2l)) / 3. Plane stride = 349520 texels.
// R3: sampler duration identical at FETCH=0 vs FETCH=122MB -> NOT HBM-bound.
// R4: stage levels 5..7 (31.5 KB, all planes) in LDS -> real win (~36%).
// R5 FAILED (1 thread/pt): broke store coalescing + occupancy -> 2.3x.
//   KEY: time scales with CONCURRENCY (latency-bound).
// R6 NEUTRAL: broadcast xyz/level loads are free.
// R7 NEUTRAL: level-uniform waves changed nothing (instr count not limiter).
// R8 NEUTRAL: single 8-load clause changed nothing (per-thread MLP absorbed).
// R9 (+6.5%): plane-per-block, levels 4..7 in LDS (42.5 KB): FETCH
//   120->81 MB, per-wave throughput 1.32x -- but 3 blk/CU = 24 waves
//   (occupancy 51%) gave back a third. Lever works; concurrency lost.
// R10 (this round): same structure, block 512 -> 1024 threads (512 pts).
//   2 blocks/CU x 16 waves = 32 waves/CU (LDS 85 of 160 KB), VGPR=40 ok.
//   Per-CU staging redundancy 3->2 copies. Everything else byte-identical.
//   Predict dur 62 -> ~47-53 us; if occupancy recovers but time doesn't,
//   the concurrency model dies too -> gather-rate roofline.

typedef float        f4v   __attribute__((ext_vector_type(4)));
typedef unsigned int u32x2 __attribute__((ext_vector_type(2)));
typedef unsigned int u32x4 __attribute__((ext_vector_type(4)));

#define FM_PLANE_STRIDE (262144 * 16)   // floats per plane in fm
#define WS_PLANE_STRIDE (87376 * 16)    // floats per plane, fp32 fallback pyramid
#define PSTRIDE_H (349520 * 16)         // halfs per plane, fp16 full pyramid
#define WS_H_BYTES (3ull * PSTRIDE_H * 2ull)
#define LVL4_OFF 348160u                // texel offset of level 4 (levels 4..7 contiguous)

__device__ __forceinline__ unsigned lvl_off(int l) {   // texel offset of level l
    return (1048576u - (1048576u >> (2 * l))) / 3u;
}

__device__ __forceinline__ f4v ld4(const float* p) {
    return *reinterpret_cast<const f4v*>(p);
}
__device__ __forceinline__ f4v ld4nt(const float* p) {
    return __builtin_nontemporal_load(reinterpret_cast<const f4v*>(p));
}
__device__ __forceinline__ void st4(float* p, f4v v) {
    *reinterpret_cast<f4v*>(p) = v;
}
__device__ __forceinline__ void st4nt(float* p, f4v v) {
    __builtin_nontemporal_store(v, reinterpret_cast<f4v*>(p));
}
__device__ __forceinline__ f4v ldraw_h(const __half* p) {   // 8 halfs as raw f4v
    return *reinterpret_cast<const f4v*>(p);
}
__device__ __forceinline__ u32x2 pack4(f4v v) {             // 4 floats -> 4 halfs
    __half2 lo = __floats2half2_rn(v.x, v.y);
    __half2 hi = __floats2half2_rn(v.z, v.w);
    u32x2 r;
    r.x = *reinterpret_cast<unsigned*>(&lo);
    r.y = *reinterpret_cast<unsigned*>(&hi);
    return r;
}
__device__ __forceinline__ f4v h4f(const __half* p) {       // 4 halfs -> 4 floats
    u32x2 u = *reinterpret_cast<const u32x2*>(p);
    unsigned a0 = u.x, a1 = u.y;
    __half2 lo = *reinterpret_cast<__half2*>(&a0);
    __half2 hi = *reinterpret_cast<__half2*>(&a1);
    float2 flo = __half22float2(lo), fhi = __half22float2(hi);
    f4v r; r.x = flo.x; r.y = flo.y; r.z = fhi.x; r.w = fhi.y;
    return r;
}
__device__ __forceinline__ float2 up2(float rawcomp) {      // 2 packed halfs -> 2 floats
    unsigned u = __float_as_uint(rawcomp);
    __half2 hh = *reinterpret_cast<__half2*>(&u);
    return __half22float2(hh);
}

// ---------------- fp16 path ----------------

// fm (fp32) -> L0' (fp16) + L1 (fp16). Thread per (L1 texel, quad q); grid (1024, 3).
__global__ __launch_bounds__(256) void mip_convert_l1(
    const float* __restrict__ fm, __half* __restrict__ wsh)
{
    int t = blockIdx.x * 256 + threadIdx.x;
    const int p = blockIdx.y;
    const int q = t & 3, idx = t >> 2;
    const int y = idx >> 8, x = idx & 255;
    const float* sp = fm + (size_t)p * FM_PLANE_STRIDE
                         + ((size_t)(2 * y) * 512 + 2 * x) * 16 + q * 4;
    f4v a = ld4nt(sp);
    f4v b = ld4nt(sp + 16);
    f4v c = ld4nt(sp + 512 * 16);
    f4v d = ld4nt(sp + 512 * 16 + 16);
    __half* L0 = wsh + (size_t)p * PSTRIDE_H;
    size_t o00 = ((size_t)(2 * y) * 512 + 2 * x) * 16 + q * 4;
    *reinterpret_cast<u32x2*>(L0 + o00)                 = pack4(a);
    *reinterpret_cast<u32x2*>(L0 + o00 + 16)            = pack4(b);
    *reinterpret_cast<u32x2*>(L0 + o00 + 512 * 16)      = pack4(c);
    *reinterpret_cast<u32x2*>(L0 + o00 + 512 * 16 + 16) = pack4(d);
    f4v m = (a + b + c + d) * 0.25f;   // L1 from fp32 source, single rounding
    __half* L1 = wsh + (size_t)p * PSTRIDE_H + (size_t)262144 * 16;
    *reinterpret_cast<u32x2*>(L1 + ((size_t)y * 256 + x) * 16 + q * 4) = pack4(m);
}

// Fused L2..L7 (fp16). Block = (32x32 L2 tile, quad q, plane p); grid (16,4,3).
__global__ __launch_bounds__(256) void mip_tail_h(__half* __restrict__ wsh)
{
    const int tile = blockIdx.x;
    const int q    = blockIdx.y;
    const int p    = blockIdx.z;
    const int ty = tile >> 2, tx = tile & 3;
    const int tid = threadIdx.x;

    __shared__ f4v A[32 * 32];
    __shared__ f4v B[16 * 16];

    __half* plane = wsh + (size_t)p * PSTRIDE_H;
    const __half* L1 = plane + (size_t)lvl_off(1) * 16;
    __half* L2 = plane + (size_t)lvl_off(2) * 16;
    __half* L3 = plane + (size_t)lvl_off(3) * 16;
    __half* L4 = plane + (size_t)lvl_off(4) * 16;
    __half* L5 = plane + (size_t)lvl_off(5) * 16;
    __half* L6 = plane + (size_t)lvl_off(6) * 16;
    __half* L7 = plane + (size_t)lvl_off(7) * 16;

    #pragma unroll
    for (int k = 0; k < 4; ++k) {
        int li = tid + k * 256;
        int ly = li >> 5, lx = li & 31;
        int gy = ty * 32 + ly, gx = tx * 32 + lx;
        const __half* sp = L1 + ((size_t)(2 * gy) * 256 + 2 * gx) * 16 + q * 4;
        f4v r = (h4f(sp) + h4f(sp + 16) + h4f(sp + 256 * 16) + h4f(sp + 256 * 16 + 16)) * 0.25f;
        A[li] = r;
        *reinterpret_cast<u32x2*>(L2 + ((size_t)gy * 128 + gx) * 16 + q * 4) = pack4(r);
    }
    __syncthreads();

    {   // L3: 16x16
        int ly = tid >> 4, lx = tid & 15;
        f4v r = (A[(2 * ly) * 32 + 2 * lx]     + A[(2 * ly) * 32 + 2 * lx + 1] +
                 A[(2 * ly + 1) * 32 + 2 * lx] + A[(2 * ly + 1) * 32 + 2 * lx + 1]) * 0.25f;
        B[tid] = r;
        *reinterpret_cast<u32x2*>(L3 + ((size_t)(ty * 16 + ly) * 64 + tx * 16 + lx) * 16 + q * 4) = pack4(r);
    }
    __syncthreads();

    if (tid < 64) {   // L4: 8x8
        int ly = tid >> 3, lx = tid & 7;
        f4v r = (B[(2 * ly) * 16 + 2 * lx]     + B[(2 * ly) * 16 + 2 * lx + 1] +
                 B[(2 * ly + 1) * 16 + 2 * lx] + B[(2 * ly + 1) * 16 + 2 * lx + 1]) * 0.25f;
        A[tid] = r;
        *reinterpret_cast<u32x2*>(L4 + ((size_t)(ty * 8 + ly) * 32 + tx * 8 + lx) * 16 + q * 4) = pack4(r);
    }
    __syncthreads();

    if (tid < 16) {   // L5: 4x4
        int ly = tid >> 2, lx = tid & 3;
        f4v r = (A[(2 * ly) * 8 + 2 * lx]     + A[(2 * ly) * 8 + 2 * lx + 1] +
                 A[(2 * ly + 1) * 8 + 2 * lx] + A[(2 * ly + 1) * 8 + 2 * lx + 1]) * 0.25f;
        B[tid] = r;
        *reinterpret_cast<u32x2*>(L5 + ((size_t)(ty * 4 + ly) * 16 + tx * 4 + lx) * 16 + q * 4) = pack4(r);
    }
    __syncthreads();

    if (tid < 4) {    // L6: 2x2
        int ly = tid >> 1, lx = tid & 1;
        f4v r = (B[(2 * ly) * 4 + 2 * lx]     + B[(2 * ly) * 4 + 2 * lx + 1] +
                 B[(2 * ly + 1) * 4 + 2 * lx] + B[(2 * ly + 1) * 4 + 2 * lx + 1]) * 0.25f;
        A[tid] = r;
        *reinterpret_cast<u32x2*>(L6 + ((size_t)(ty * 2 + ly) * 8 + tx * 2 + lx) * 16 + q * 4) = pack4(r);
    }
    __syncthreads();

    if (tid == 0) {   // L7: 1 texel
        f4v r = (A[0] + A[1] + A[2] + A[3]) * 0.25f;
        *reinterpret_cast<u32x2*>(L7 + ((size_t)ty * 4 + tx) * 16 + q * 4) = pack4(r);
    }
}

// Issue the 4 bilinear tap loads for one level WITHOUT consuming them.
// wplane = fp16 pyramid base of this block's plane. Levels >= 4 read the
// LDS copy (this plane's levels 4..7 staged linearly from texel LVL4_OFF).
__device__ __forceinline__ void tap_issue(
    const __half* __restrict__ wplane, const __half* __restrict__ lds_h,
    int l, float u, float v, int h,
    f4v& q00, f4v& q01, f4v& q10, f4v& q11, float& fx, float& fy)
{
    const int sz = 512 >> l;
    const float fsz = (float)sz;
    float px = u * fsz - 0.5f;
    float py = v * fsz - 0.5f;
    float xf = floorf(px), yf = floorf(py);
    fx = px - xf;
    fy = py - yf;
    int xi = (int)xf, yi = (int)yf;
    int xa = min(max(xi, 0), sz - 1);
    int xb = min(xi + 1, sz - 1);      // xi >= -1 always
    int ya = min(max(yi, 0), sz - 1);
    int yb = min(yi + 1, sz - 1);
    if (l >= 4) {
        const __half* base = lds_h + (size_t)(lvl_off(l) - LVL4_OFF) * 16 + h * 8;
        const __half* r0 = base + (ya * sz) * 16;
        const __half* r1 = base + (yb * sz) * 16;
        q00 = ldraw_h(r0 + xa * 16);
        q01 = ldraw_h(r0 + xb * 16);
        q10 = ldraw_h(r1 + xa * 16);
        q11 = ldraw_h(r1 + xb * 16);
    } else {
        const __half* base = wplane + (size_t)lvl_off(l) * 16 + h * 8;
        const __half* r0 = base + (size_t)(ya * sz) * 16;
        const __half* r1 = base + (size_t)(yb * sz) * 16;
        q00 = ldraw_h(r0 + (size_t)xa * 16);
        q01 = ldraw_h(r0 + (size_t)xb * 16);
        q10 = ldraw_h(r1 + (size_t)xa * 16);
        q11 = ldraw_h(r1 + (size_t)xb * 16);
    }
}

// One plane per block (blockIdx.y = p); 2 threads per point (h = tid&1),
// 512 points per 1024-thread block. LDS: this plane's levels 4..7
// (1360 texels * 32 B = 42.5 KB). 2 blocks/CU x 16 waves = 32 waves/CU
// (wave-cap-limited; LDS 85 of 160 KB). VGPR=40 -> 8 waves/SIMD ok.
__global__ __launch_bounds__(1024) void trimip_sample_h(
    const float* __restrict__ xyz, const float* __restrict__ level,
    const __half* __restrict__ wsh, float* __restrict__ out, int N)
{
    __shared__ u32x4 lds[2720];       // 1360 texels * 32 B
    const int p = blockIdx.y;
    const __half* wplane = wsh + (size_t)p * PSTRIDE_H;
    for (int uidx = threadIdx.x; uidx < 2720; uidx += 1024) {
        lds[uidx] = *reinterpret_cast<const u32x4*>(
            wplane + (size_t)LVL4_OFF * 16 + (size_t)uidx * 8);
    }
    __syncthreads();
    const __half* lds_h = reinterpret_cast<const __half*>(lds);

    const int n = blockIdx.x * 512 + (threadIdx.x >> 1);
    if (n >= N) return;
    const int h = threadIdx.x & 1;

    const float c0 = xyz[n * 3 + 0];
    const float c1 = xyz[n * 3 + 1];
    const float c2 = xyz[n * 3 + 2];
    const float u = (p == 0) ? c1 : c0;
    const float v = (p == 2) ? c1 : c2;

    float lv = level[n];
    lv = fminf(fmaxf(lv, 0.f), 7.f);
    float lf = floorf(lv);
    float f = lv - lf;
    int l0 = (int)lf;
    int l1 = min(l0 + 1, 7);

    // Issue all 8 tap loads before consuming any.
    f4v a00, a01, a10, a11, b00, b01, b10, b11;
    float fx0, fy0, fx1, fy1;
    tap_issue(wplane, lds_h, l0, u, v, h, a00, a01, a10, a11, fx0, fy0);
    tap_issue(wplane, lds_h, l1, u, v, h, b00, b01, b10, b11, fx1, fy1);

    float s0[8], s1[8];
    {
        float gx = 1.f - fx0, gy = 1.f - fy0;
        float w00 = gx * gy, w01 = fx0 * gy, w10 = gx * fy0, w11 = fx0 * fy0;
        #pragma unroll
        for (int i = 0; i < 4; ++i) {
            float2 a = up2(a00[i]), b = up2(a01[i]), c = up2(a10[i]), d = up2(a11[i]);
            s0[2 * i]     = a.x * w00 + b.x * w01 + c.x * w10 + d.x * w11;
            s0[2 * i + 1] = a.y * w00 + b.y * w01 + c.y * w10 + d.y * w11;
        }
    }
    {
        float gx = 1.f - fx1, gy = 1.f - fy1;
        float w00 = gx * gy, w01 = fx1 * gy, w10 = gx * fy1, w11 = fx1 * fy1;
        #pragma unroll
        for (int i = 0; i < 4; ++i) {
            float2 a = up2(b00[i]), b = up2(b01[i]), c = up2(b10[i]), d = up2(b11[i]);
            s1[2 * i]     = a.x * w00 + b.x * w01 + c.x * w10 + d.x * w11;
            s1[2 * i + 1] = a.y * w00 + b.y * w01 + c.y * w10 + d.y * w11;
        }
    }

    float g = 1.f - f;
    f4v oa, ob;
    #pragma unroll
    for (int i = 0; i < 4; ++i) {
        oa[i] = s0[i] * g + s1[i] * f;
        ob[i] = s0[4 + i] * g + s1[4 + i] * f;
    }
    float* op = out + (size_t)((n * 3 + p) * 2 + h) * 8;
    st4nt(op, oa);
    st4nt(op + 4, ob);
}

// ---------------- fp32 fallback path ----------------

__device__ __forceinline__ f4v avg4(f4v a, f4v b, f4v c, f4v d) {
    return (a + b + c + d) * 0.25f;
}

__global__ __launch_bounds__(256) void mip_build_f(
    const float* __restrict__ src, float* __restrict__ dst)
{
    int t = blockIdx.x * blockDim.x + threadIdx.x;
    const int p = blockIdx.y;
    const int q = t & 3, idx = t >> 2;
    const int y = idx >> 8, x = idx & 255;
    const float* sp = src + (size_t)p * FM_PLANE_STRIDE
                          + ((size_t)(2 * y) * 512 + 2 * x) * 16 + q * 4;
    f4v r = avg4(ld4(sp), ld4(sp + 16), ld4(sp + 512 * 16), ld4(sp + 512 * 16 + 16));
    st4(dst + (size_t)p * WS_PLANE_STRIDE + ((size_t)y * 256 + x) * 16 + q * 4, r);
}

__global__ __launch_bounds__(256) void mip_tail_f(float* __restrict__ mips)
{
    const int tile = blockIdx.x, q = blockIdx.y, p = blockIdx.z;
    const int ty = tile >> 2, tx = tile & 3;
    const int tid = threadIdx.x;
    __shared__ f4v A[32 * 32];
    __shared__ f4v B[16 * 16];
    float* plane = mips + (size_t)p * WS_PLANE_STRIDE;
    const float* L1 = plane;
    float* L2 = plane + (size_t)65536 * 16;
    float* L3 = plane + (size_t)81920 * 16;
    float* L4 = plane + (size_t)86016 * 16;
    float* L5 = plane + (size_t)87040 * 16;
    float* L6 = plane + (size_t)87296 * 16;
    float* L7 = plane + (size_t)87360 * 16;

    #pragma unroll
    for (int k = 0; k < 4; ++k) {
        int li = tid + k * 256;
        int ly = li >> 5, lx = li & 31;
        int gy = ty * 32 + ly, gx = tx * 32 + lx;
        const float* sp = L1 + ((size_t)(2 * gy) * 256 + 2 * gx) * 16 + q * 4;
        f4v r = avg4(ld4(sp), ld4(sp + 16), ld4(sp + 256 * 16), ld4(sp + 256 * 16 + 16));
        A[li] = r;
        st4(L2 + ((size_t)gy * 128 + gx) * 16 + q * 4, r);
    }
    __syncthreads();
    {
        int ly = tid >> 4, lx = tid & 15;
        f4v r = avg4(A[(2 * ly) * 32 + 2 * lx],     A[(2 * ly) * 32 + 2 * lx + 1],
                     A[(2 * ly + 1) * 32 + 2 * lx], A[(2 * ly + 1) * 32 + 2 * lx + 1]);
        B[tid] = r;
        st4(L3 + ((size_t)(ty * 16 + ly) * 64 + tx * 16 + lx) * 16 + q * 4, r);
    }
    __syncthreads();
    if (tid < 64) {
        int ly = tid >> 3, lx = tid & 7;
        f4v r = avg4(B[(2 * ly) * 16 + 2 * lx],     B[(2 * ly) * 16 + 2 * lx + 1],
                     B[(2 * ly + 1) * 16 + 2 * lx], B[(2 * ly + 1) * 16 + 2 * lx + 1]);
        A[tid] = r;
        st4(L4 + ((size_t)(ty * 8 + ly) * 32 + tx * 8 + lx) * 16 + q * 4, r);
    }
    __syncthreads();
    if (tid < 16) {
        int ly = tid >> 2, lx = tid & 3;
        f4v r = avg4(A[(2 * ly) * 8 + 2 * lx],     A[(2 * ly) * 8 + 2 * lx + 1],
                     A[(2 * ly + 1) * 8 + 2 * lx], A[(2 * ly + 1) * 8 + 2 * lx + 1]);
        B[tid] = r;
        st4(L5 + ((size_t)(ty * 4 + ly) * 16 + tx * 4 + lx) * 16 + q * 4, r);
    }
    __syncthreads();
    if (tid < 4) {
        int ly = tid >> 1, lx = tid & 1;
        f4v r = avg4(B[(2 * ly) * 4 + 2 * lx],     B[(2 * ly) * 4 + 2 * lx + 1],
                     B[(2 * ly + 1) * 4 + 2 * lx], B[(2 * ly + 1) * 4 + 2 * lx + 1]);
        A[tid] = r;
        st4(L6 + ((size_t)(ty * 2 + ly) * 8 + tx * 2 + lx) * 16 + q * 4, r);
    }
    __syncthreads();
    if (tid == 0) {
        f4v r = avg4(A[0], A[1], A[2], A[3]);
        st4(L7 + ((size_t)ty * 4 + tx) * 16 + q * 4, r);
    }
}

__device__ __forceinline__ f4v bilerp_f(
    const float* __restrict__ fm, const float* __restrict__ mips,
    int p, int l, float u, float v, int q)
{
    const int sz = 512 >> l;
    const float fsz = (float)sz;
    float px = u * fsz - 0.5f;
    float py = v * fsz - 0.5f;
    float xf = floorf(px), yf = floorf(py);
    float fx = px - xf, fy = py - yf;
    int xi = (int)xf, yi = (int)yf;
    int xa = min(max(xi, 0), sz - 1);
    int xb = min(xi + 1, sz - 1);
    int ya = min(max(yi, 0), sz - 1);
    int yb = min(yi + 1, sz - 1);
    const float* base;
    if (l == 0) {
        base = fm + (size_t)p * FM_PLANE_STRIDE;
    } else {
        unsigned off = (262144u - ((unsigned)(sz * sz) << 2)) / 3u;
        base = mips + (size_t)p * WS_PLANE_STRIDE + (size_t)off * 16;
    }
    const float* r0 = base + (size_t)(ya * sz) * 16 + q * 4;
    const float* r1 = base + (size_t)(yb * sz) * 16 + q * 4;
    f4v f00 = ld4(r0 + xa * 16);
    f4v f01 = ld4(r0 + xb * 16);
    f4v f10 = ld4(r1 + xa * 16);
    f4v f11 = ld4(r1 + xb * 16);
    float gx = 1.f - fx, gy = 1.f - fy;
    return (f00 * gx + f01 * fx) * gy + (f10 * gx + f11 * fx) * fy;
}

__global__ __launch_bounds__(256) void trimip_sample_f(
    const float* __restrict__ xyz, const float* __restrict__ level,
    const float* __restrict__ fm, const float* __restrict__ mips,
    float* __restrict__ out, int N)
{
    int t = blockIdx.x * blockDim.x + threadIdx.x;
    if (t >= N * 12) return;
    const int q = t & 3;
    const int r = t >> 2;
    const int n = r / 3;
    const int p = r - n * 3;
    const float c0 = xyz[n * 3 + 0];
    const float c1 = xyz[n * 3 + 1];
    const float c2 = xyz[n * 3 + 2];
    const float u = (p == 0) ? c1 : c0;
    const float v = (p == 2) ? c1 : c2;
    float lv = level[n];
    lv = fminf(fmaxf(lv, 0.f), 7.f);
    float lf = floorf(lv);
    float f = lv - lf;
    int l0 = (int)lf;
    int l1 = min(l0 + 1, 7);
    f4v s0 = bilerp_f(fm, mips, p, l0, u, v, q);
    f4v s1 = bilerp_f(fm, mips, p, l1, u, v, q);
    f4v o = s0 * (1.f - f) + s1 * f;
    st4nt(out + (size_t)t * 4, o);
}

extern "C" void kernel_launch(void* const* d_in, const int* in_sizes, int n_in,
                              void* d_out, int out_size, void* d_ws, size_t ws_size,
                              hipStream_t stream) {
    const float* xyz   = (const float*)d_in[0];
    const float* level = (const float*)d_in[1];
    const float* fm    = (const float*)d_in[2];
    float* out = (float*)d_out;
    const int N = in_sizes[1];

    if (ws_size >= WS_H_BYTES) {
        __half* wsh = (__half*)d_ws;
        mip_convert_l1<<<dim3(1024, 3), dim3(256), 0, stream>>>(fm, wsh);
        mip_tail_h<<<dim3(16, 4, 3), dim3(256), 0, stream>>>(wsh);
        trimip_sample_h<<<dim3((N + 511) / 512, 3), 1024, 0, stream>>>(
            xyz, level, wsh, out, N);
    } else {
        float* mips = (float*)d_ws;
        mip_build_f<<<dim3(1024, 3), dim3(256), 0, stream>>>(fm, mips);
        mip_tail_f<<<dim3(16, 4, 3), dim3(256), 0, stream>>>(mips);
        const int total = N * 12;
        trimip_sample_f<<<(total + 255) / 256, 256, 0, stream>>>(xyz, level, fm, mips, out, N);
    }
}